// Round 16
// baseline (1528.199 us; speedup 1.0000x reference)
//
#include <hip/hip_runtime.h>
#include <stdint.h>

#define B_   8192
#define IN_  2048
#define H0_  1024
#define H1_  512
#define D_   256
#define Q_   8
#define K_   2048

typedef unsigned long long u64;
typedef unsigned short u16;
typedef __attribute__((ext_vector_type(8))) short bf16x8;
typedef __attribute__((ext_vector_type(4))) float f32x4;

__device__ __forceinline__ u16 f2bf(float x) {
    unsigned u = __float_as_uint(x);
    return (u16)((u + 0x7fffu + ((u >> 16) & 1u)) >> 16);
}
__device__ __forceinline__ float bf2f(u16 h) {
    return __uint_as_float((unsigned)h << 16);
}
__device__ __forceinline__ void gload_lds16(const void* g, void* l) {
    __builtin_amdgcn_global_load_lds(
        (const __attribute__((address_space(1))) void*)g,
        (__attribute__((address_space(3))) void*)l, 16, 0, 0);
}
__device__ __forceinline__ unsigned fkey(float f) {
    unsigned u = __float_as_uint(f);
    return (u & 0x80000000u) ? ~u : (u | 0x80000000u);
}

#define MFMA_BF16 __builtin_amdgcn_mfma_f32_16x16x32_bf16

// =====================================================================
// cbpack: codebooks -> bf16x3 planes in MFMA fragment order.
// group g = q*1024 + cg*8 + k; lane l: col cg*16+(l&15), dims k*32+(l>>4)*8.
// =====================================================================
__global__ __launch_bounds__(256)
void cbpack_kernel(const float* __restrict__ cb, u16* __restrict__ f0,
                   u16* __restrict__ f1, u16* __restrict__ f2)
{
    const int g    = blockIdx.x * 4 + (threadIdx.x >> 6);  // 0..8191
    const int lane = threadIdx.x & 63;
    const int q = g >> 10, rem = g & 1023, cg = rem >> 3, k = rem & 7;
    const int col = cg * 16 + (lane & 15);
    const int d0  = k * 32 + (lane >> 4) * 8;
    const float* src = cb + ((size_t)q * K_ + col) * D_ + d0;
    float4 va = *(const float4*)src, vb = *(const float4*)(src + 4);
    float xs[8] = {va.x, va.y, va.z, va.w, vb.x, vb.y, vb.z, vb.w};
    u16 h[8], m[8], l8[8];
#pragma unroll
    for (int e = 0; e < 8; e++) {
        h[e] = f2bf(xs[e]);
        float r1 = xs[e] - bf2f(h[e]);
        m[e] = f2bf(r1);
        r1 -= bf2f(m[e]);
        l8[e] = f2bf(r1);
    }
    const size_t off = ((size_t)g * 64 + lane) * 8;
    *(ushort4*)(f0 + off)     = make_ushort4(h[0], h[1], h[2], h[3]);
    *(ushort4*)(f0 + off + 4) = make_ushort4(h[4], h[5], h[6], h[7]);
    *(ushort4*)(f1 + off)     = make_ushort4(m[0], m[1], m[2], m[3]);
    *(ushort4*)(f1 + off + 4) = make_ushort4(m[4], m[5], m[6], m[7]);
    *(ushort4*)(f2 + off)     = make_ushort4(l8[0], l8[1], l8[2], l8[3]);
    *(ushort4*)(f2 + off + 4) = make_ushort4(l8[4], l8[5], l8[6], l8[7]);
}

// ---- shared helper: write one 8-dim chunk of row into packed A-planes ----
// A-plane layout: group ga = (row>>4)*8 + k (k = kc>>2); lane = (row&15) +
// (kc&3)*16; dims covered = kc*8 .. +8  (row within 16-row fragment group).
__device__ __forceinline__ void apack_write(u16* ap0, u16* ap1, u16* ap2,
                                            int row, int kc, const float* d)
{
    int ga = (row >> 4) * 8 + (kc >> 2);
    int lane_in = (row & 15) + (kc & 3) * 16;
    size_t o = ((size_t)ga * 64 + lane_in) * 8;
    u16 h[8], m[8], l[8];
#pragma unroll
    for (int e = 0; e < 8; e++) {
        h[e] = f2bf(d[e]);
        float r1 = d[e] - bf2f(h[e]);
        m[e] = f2bf(r1);
        r1 -= bf2f(m[e]);
        l[e] = f2bf(r1);
    }
    *(ushort4*)(ap0 + o)     = make_ushort4(h[0], h[1], h[2], h[3]);
    *(ushort4*)(ap0 + o + 4) = make_ushort4(h[4], h[5], h[6], h[7]);
    *(ushort4*)(ap1 + o)     = make_ushort4(m[0], m[1], m[2], m[3]);
    *(ushort4*)(ap1 + o + 4) = make_ushort4(m[4], m[5], m[6], m[7]);
    *(ushort4*)(ap2 + o)     = make_ushort4(l[0], l[1], l[2], l[3]);
    *(ushort4*)(ap2 + o + 4) = make_ushort4(l[4], l[5], l[6], l[7]);
}

// ---- initial A-plane pack from z ----
__global__ __launch_bounds__(256)
void apack_init(const float* __restrict__ z, u16* __restrict__ ap0,
                u16* __restrict__ ap1, u16* __restrict__ ap2)
{
    const int row = blockIdx.x * 16 + (threadIdx.x >> 4);
    const int dc  = threadIdx.x & 15;
#pragma unroll
    for (int j = 0; j < 2; j++) {
        int kc = dc * 2 + j;
        float d[8];
        const float* src = z + (size_t)row * D_ + kc * 8;
        float4 v0 = *(const float4*)src, v1 = *(const float4*)(src + 4);
        d[0] = v0.x; d[1] = v0.y; d[2] = v0.z; d[3] = v0.w;
        d[4] = v1.x; d[5] = v1.y; d[6] = v1.z; d[7] = v1.w;
        apack_write(ap0, ap1, ap2, row, kc, d);
    }
}

// =====================================================================
// dist_kernel: one VQ stage's distance+argmin. LDS-free MFMA (A and B
// both from fragment-packed global planes -> every load is a coalesced
// 1KB wave read) => 256 thr, ~0.5KB LDS, need-based VGPR, 8 blocks/CU
// = 32 waves/CU (4x R12). Wave w: rows (w>>1)*16 of the block's 32,
// col-half (w&1)*1024. Per-row argmin over the wave's 1024 cols, then
// 2-way combine in LDS; winner u64 written per row (no atomics).
// =====================================================================
__global__ __launch_bounds__(256)
void dist_kernel(const u16* __restrict__ ap0, const u16* __restrict__ ap1,
                 const u16* __restrict__ ap2,
                 const u16* __restrict__ cbF0, const u16* __restrict__ cbF1,
                 const u16* __restrict__ cbF2,
                 const float* __restrict__ cnorm,
                 u64* __restrict__ winners, float* __restrict__ out_idx,
                 int q)
{
    __shared__ u64 wmin[32][2];
    const int tid  = threadIdx.x;
    const int lane = tid & 63;
    const int wv   = tid >> 6;
    const int row0 = blockIdx.x * 32;
    const int ra   = (wv >> 1) * 16;           // 0 or 16
    const int ch   = wv & 1;                   // col half
    const int rbg  = blockIdx.x * 2 + (wv >> 1);
    const float* cnq = cnorm + (size_t)q * K_;

    u64 best4[4] = {~0ull, ~0ull, ~0ull, ~0ull};

    for (int g = 0; g < 16; g++) {
        const int cg0 = ch * 64 + g * 4;       // 16-col group base (0..127)
        f32x4 acc[4];
#pragma unroll
        for (int n = 0; n < 4; n++) acc[n] = (f32x4){0.f, 0.f, 0.f, 0.f};

#pragma unroll
        for (int k = 0; k < 8; k++) {
            size_t fa = (((size_t)rbg * 8 + k) * 64 + lane) * 8;
            bf16x8 a0 = *(const bf16x8*)(ap0 + fa);
            bf16x8 a1 = *(const bf16x8*)(ap1 + fa);
            bf16x8 a2 = *(const bf16x8*)(ap2 + fa);
            bf16x8 b0[4], b1[4], b2[4];
#pragma unroll
            for (int n = 0; n < 4; n++) {
                size_t fb = (((size_t)(q << 10) + (cg0 + n) * 8 + k) << 9)
                            + lane * 8;
                b0[n] = *(const bf16x8*)(cbF0 + fb);
                b1[n] = *(const bf16x8*)(cbF1 + fb);
                b2[n] = *(const bf16x8*)(cbF2 + fb);
            }
#pragma unroll
            for (int n = 0; n < 4; n++) {
                acc[n] = MFMA_BF16(a0, b0[n], acc[n], 0, 0, 0);
                acc[n] = MFMA_BF16(a1, b0[n], acc[n], 0, 0, 0);
                acc[n] = MFMA_BF16(a0, b1[n], acc[n], 0, 0, 0);
                acc[n] = MFMA_BF16(a1, b1[n], acc[n], 0, 0, 0);
                acc[n] = MFMA_BF16(a2, b0[n], acc[n], 0, 0, 0);
                acc[n] = MFMA_BF16(a0, b2[n], acc[n], 0, 0, 0);
            }
        }
#pragma unroll
        for (int n = 0; n < 4; n++) {
            int col = (cg0 + n) * 16 + (lane & 15);
            float cn = cnq[col];
#pragma unroll
            for (int r = 0; r < 4; r++) {
                float d = cn - 2.0f * acc[n][r];
                u64 p = ((u64)fkey(d) << 32) | (unsigned)col;
                if (p < best4[r]) best4[r] = p;
            }
        }
    }

    // fold across the 16 columns held by lanes (same lane>>4 group)
#pragma unroll
    for (int r = 0; r < 4; r++) {
        u64 p = best4[r];
#pragma unroll
        for (int msk = 1; msk <= 8; msk <<= 1) {
            u64 o = __shfl_xor(p, msk, 64);
            if (o < p) p = o;
        }
        if ((lane & 15) == 0)
            wmin[ra + (lane >> 4) * 4 + r][ch] = p;
    }
    __syncthreads();
    if (tid < 32) {
        u64 m = wmin[tid][0];
        u64 o = wmin[tid][1];
        if (o < m) m = o;
        winners[row0 + tid] = m;
        out_idx[(size_t)(row0 + tid) * Q_ + q] = (float)(unsigned)(m & 0xffffffffu);
    }
}

// =====================================================================
// vq_update: gather winner codeword, fp32 residual update, loss, and
// write next stage's packed A-planes (or qplane at q==7).
// grid B_/16, 256 threads; thread = (row, 16-dim slice).
// =====================================================================
__global__ __launch_bounds__(256)
void vq_update(const u64* __restrict__ winners, const float* __restrict__ z,
               const float* __restrict__ CB, float* __restrict__ resid,
               u16* __restrict__ ap0, u16* __restrict__ ap1,
               u16* __restrict__ ap2, u16* __restrict__ qplane,
               float* __restrict__ loss_acc, int q)
{
    const int tid  = threadIdx.x;
    const int lane = tid & 63;
    const int row  = blockIdx.x * 16 + (tid >> 4);
    const int dc   = tid & 15;
    const unsigned idx = (unsigned)(winners[row] & 0xffffffffu);
    const float* rsrc = (q == 0) ? z : resid;
    const size_t off = (size_t)row * D_ + dc * 16;
    const float* cw = CB + ((size_t)q * K_ + idx) * D_ + dc * 16;

    float d[16];
    float lsum = 0.f;
#pragma unroll
    for (int e = 0; e < 16; e += 4) {
        float4 rv = *(const float4*)(rsrc + off + e);
        float4 cv = *(const float4*)(cw + e);
        d[e]     = rv.x - cv.x;
        d[e + 1] = rv.y - cv.y;
        d[e + 2] = rv.z - cv.z;
        d[e + 3] = rv.w - cv.w;
        lsum += d[e] * d[e] + d[e+1] * d[e+1] + d[e+2] * d[e+2] + d[e+3] * d[e+3];
    }

    if (q < Q_ - 1) {
#pragma unroll
        for (int e = 0; e < 16; e += 4)
            *(float4*)(resid + off + e) = make_float4(d[e], d[e+1], d[e+2], d[e+3]);
#pragma unroll
        for (int j = 0; j < 2; j++)
            apack_write(ap0, ap1, ap2, row, dc * 2 + j, d + j * 8);
    } else {
#pragma unroll
        for (int e = 0; e < 16; e += 8) {
            float4 z0 = *(const float4*)(z + off + e);
            float4 z1 = *(const float4*)(z + off + e + 4);
            *(ushort4*)(qplane + off + e) = make_ushort4(
                f2bf(z0.x - d[e]),     f2bf(z0.y - d[e + 1]),
                f2bf(z0.z - d[e + 2]), f2bf(z0.w - d[e + 3]));
            *(ushort4*)(qplane + off + e + 4) = make_ushort4(
                f2bf(z1.x - d[e + 4]), f2bf(z1.y - d[e + 5]),
                f2bf(z1.z - d[e + 6]), f2bf(z1.w - d[e + 7]));
        }
    }

#pragma unroll
    for (int o = 32; o > 0; o >>= 1) lsum += __shfl_down(lsum, o, 64);
    if (lane == 0) atomicAdd(&loss_acc[q], lsum);
}

// =====================================================================
// gemm2: 256x128 tile, 512 threads, 2-phase prefetch, XCD swizzle
// =====================================================================
template<int NSA, int NSB, int RELU, int NSO, int WF32>
__global__ __launch_bounds__(512)
void gemm2(const u16* __restrict__ A0, const u16* __restrict__ A1,
           const u16* __restrict__ A2,
           const u16* __restrict__ B0, const u16* __restrict__ B1,
           const u16* __restrict__ B2,
           const float* __restrict__ bias,
           float* __restrict__ C,
           u16* __restrict__ C0, u16* __restrict__ C1, u16* __restrict__ C2,
           int N, int Kd)
{
    constexpr int HALF = NSA * 16384 + NSB * 8192;
    __shared__ __align__(16) char smem[2 * HALF];
    const int tid  = threadIdx.x;
    const int lane = tid & 63;
    const int wid  = tid >> 6;
    const int wr   = wid >> 1, wc = wid & 1;

    const int nwg  = gridDim.x;
    const int orig = blockIdx.x;
    const int xcd  = orig & 7;
    const int q8 = nwg >> 3, r8 = nwg & 7;
    const int wgid = (xcd < r8 ? xcd * (q8 + 1)
                               : r8 * (q8 + 1) + (xcd - r8) * q8) + (orig >> 3);
    const int gx = N >> 7;
    const int bx = wgid % gx;
    const int by = wgid / gx;
    const int row0 = by * 256;
    const int col0 = bx * 128;

    const u16* asrc[3][2];
    const u16* bsrc[3];
#pragma unroll
    for (int h = 0; h < 2; h++) {
        int ch = h * 512 + tid;
        int r  = ch >> 2;
        int kc = (ch & 3) ^ ((r >> 1) & 3);
        size_t off = (size_t)(row0 + r) * Kd + kc * 8;
        asrc[0][h] = A0 + off;
        if constexpr (NSA >= 3) { asrc[1][h] = A1 + off; asrc[2][h] = A2 + off; }
    }
    {
        int r  = tid >> 2;
        int kc = (tid & 3) ^ ((r >> 1) & 3);
        size_t off = (size_t)(col0 + r) * Kd + kc * 8;
        bsrc[0] = B0 + off;
        if constexpr (NSB >= 3) { bsrc[1] = B1 + off; bsrc[2] = B2 + off; }
    }

    auto stage = [&](int c) {
        char* base = smem + c * HALF;
#pragma unroll
        for (int s = 0; s < NSA; s++)
#pragma unroll
            for (int h = 0; h < 2; h++) {
                gload_lds16(asrc[s][h], base + s * 16384 + (h * 512 + tid) * 16);
                asrc[s][h] += 32;
            }
#pragma unroll
        for (int s = 0; s < NSB; s++) {
            gload_lds16(bsrc[s], base + NSA * 16384 + s * 8192 + tid * 16);
            bsrc[s] += 32;
        }
    };

    f32x4 acc[4][4];
#pragma unroll
    for (int m = 0; m < 4; m++)
#pragma unroll
        for (int n = 0; n < 4; n++) acc[m][n] = (f32x4){0.f, 0.f, 0.f, 0.f};

    const unsigned fro = (unsigned)((lane & 15) * 64
        + (((lane >> 4) ^ (((lane & 15) >> 1) & 3)) * 16));

    const int nt = Kd >> 5;
    int cur = 0;
    stage(0);
    __syncthreads();

    for (int t = 0; t < nt; t++) {
        if (t + 1 < nt) stage(cur ^ 1);
        const char* base = smem + cur * HALF;
        bf16x8 bfr[4][3];
#pragma unroll
        for (int n = 0; n < 4; n++)
#pragma unroll
            for (int s = 0; s < NSB; s++)
                bfr[n][s] = *(const bf16x8*)(base + NSA * 16384 + s * 8192
                                             + (wc * 64 + n * 16) * 64 + fro);
#pragma unroll
        for (int m = 0; m < 4; m++) {
            bf16x8 af[3];
#pragma unroll
            for (int s = 0; s < NSA; s++)
                af[s] = *(const bf16x8*)(base + s * 16384
                                         + (wr * 64 + m * 16) * 64 + fro);
#pragma unroll
            for (int n = 0; n < 4; n++) {
                acc[m][n] = MFMA_BF16(af[0], bfr[n][0], acc[m][n], 0, 0, 0);
                if constexpr (NSA >= 3 && NSB >= 3) {
                    acc[m][n] = MFMA_BF16(af[1], bfr[n][0], acc[m][n], 0, 0, 0);
                    acc[m][n] = MFMA_BF16(af[0], bfr[n][1], acc[m][n], 0, 0, 0);
                    acc[m][n] = MFMA_BF16(af[1], bfr[n][1], acc[m][n], 0, 0, 0);
                    acc[m][n] = MFMA_BF16(af[2], bfr[n][0], acc[m][n], 0, 0, 0);
                    acc[m][n] = MFMA_BF16(af[0], bfr[n][2], acc[m][n], 0, 0, 0);
                }
            }
        }
        __syncthreads();
        cur ^= 1;
    }

    const int rbase = row0 + wr * 64 + (lane >> 4) * 4;
    const int cbase = col0 + wc * 64 + (lane & 15);
    float bv[4];
#pragma unroll
    for (int n = 0; n < 4; n++) bv[n] = bias[cbase + n * 16];
#pragma unroll
    for (int m = 0; m < 4; m++)
#pragma unroll
        for (int n = 0; n < 4; n++)
#pragma unroll
            for (int r = 0; r < 4; r++) {
                float o = acc[m][n][r] + bv[n];
                if constexpr (RELU) o = fmaxf(o, 0.f);
                size_t off = (size_t)(rbase + m * 16 + r) * N + (cbase + n * 16);
                if constexpr (WF32) C[off] = o;
                if constexpr (NSO >= 1) {
                    u16 p0 = f2bf(o);
                    C0[off] = p0;
                    if constexpr (NSO >= 3) {
                        float r1 = o - bf2f(p0);
                        u16 p1 = f2bf(r1);
                        C1[off] = p1;
                        r1 -= bf2f(p1);
                        C2[off] = f2bf(r1);
                    }
                }
            }
}

// =====================================================================
// gemm_mfma: 128x128 / 4-wave kernel (small-N GEMMs: enc G2/G3, dec1)
// =====================================================================
template<int NSA, int NSB, int RELU, int NSO, int WF32>
__global__ __launch_bounds__(256)
void gemm_mfma(const u16* __restrict__ A0, const u16* __restrict__ A1,
               const u16* __restrict__ A2,
               const u16* __restrict__ B0, const u16* __restrict__ B1,
               const u16* __restrict__ B2,
               const float* __restrict__ bias,
               float* __restrict__ C,
               u16* __restrict__ C0, u16* __restrict__ C1, u16* __restrict__ C2,
               int M, int N, int Kd)
{
    constexpr int NP = NSA + NSB;
    __shared__ __align__(16) char smem[NP * 8192];
    const int tid  = threadIdx.x;
    const int lane = tid & 63;
    const int wid  = tid >> 6;
    const int wr   = wid >> 1, wc = wid & 1;
    const int row0 = blockIdx.y * 128;
    const int col0 = blockIdx.x * 128;

    const u16* asrc[3][2];
    const u16* bsrc[3][2];
#pragma unroll
    for (int h = 0; h < 2; h++) {
        int ch = h * 256 + tid;
        int r  = ch >> 2;
        int kc = (ch & 3) ^ ((r >> 1) & 3);
        size_t aoff = (size_t)(row0 + r) * Kd + kc * 8;
        size_t boff = (size_t)(col0 + r) * Kd + kc * 8;
        asrc[0][h] = A0 + aoff;
        if constexpr (NSA >= 3) { asrc[1][h] = A1 + aoff; asrc[2][h] = A2 + aoff; }
        bsrc[0][h] = B0 + boff;
        if constexpr (NSB >= 3) { bsrc[1][h] = B1 + boff; bsrc[2][h] = B2 + boff; }
    }

    f32x4 acc[4][4];
#pragma unroll
    for (int m = 0; m < 4; m++)
#pragma unroll
        for (int n = 0; n < 4; n++) acc[m][n] = (f32x4){0.f, 0.f, 0.f, 0.f};

    const unsigned fro = (unsigned)((lane & 15) * 64
        + (((lane >> 4) ^ (((lane & 15) >> 1) & 3)) * 16));

    for (int k0 = 0; k0 < Kd; k0 += 32) {
#pragma unroll
        for (int s = 0; s < NSA; s++)
#pragma unroll
            for (int h = 0; h < 2; h++) {
                gload_lds16(asrc[s][h], smem + s * 8192 + (h * 256 + tid) * 16);
                asrc[s][h] += 32;
            }
#pragma unroll
        for (int s = 0; s < NSB; s++)
#pragma unroll
            for (int h = 0; h < 2; h++) {
                gload_lds16(bsrc[s][h],
                            smem + (NSA + s) * 8192 + (h * 256 + tid) * 16);
                bsrc[s][h] += 32;
            }
        __syncthreads();

        bf16x8 bfr[4][3];
#pragma unroll
        for (int n = 0; n < 4; n++)
#pragma unroll
            for (int s = 0; s < NSB; s++)
                bfr[n][s] = *(const bf16x8*)(smem + (NSA + s) * 8192
                                             + (wc * 64 + n * 16) * 64 + fro);
#pragma unroll
        for (int m = 0; m < 4; m++) {
            bf16x8 af[3];
#pragma unroll
            for (int s = 0; s < NSA; s++)
                af[s] = *(const bf16x8*)(smem + s * 8192
                                         + (wr * 64 + m * 16) * 64 + fro);
#pragma unroll
            for (int n = 0; n < 4; n++) {
                acc[m][n] = MFMA_BF16(af[0], bfr[n][0], acc[m][n], 0, 0, 0);
                if constexpr (NSA >= 3 && NSB >= 3) {
                    acc[m][n] = MFMA_BF16(af[1], bfr[n][0], acc[m][n], 0, 0, 0);
                    acc[m][n] = MFMA_BF16(af[0], bfr[n][1], acc[m][n], 0, 0, 0);
                    acc[m][n] = MFMA_BF16(af[1], bfr[n][1], acc[m][n], 0, 0, 0);
                    acc[m][n] = MFMA_BF16(af[2], bfr[n][0], acc[m][n], 0, 0, 0);
                    acc[m][n] = MFMA_BF16(af[0], bfr[n][2], acc[m][n], 0, 0, 0);
                }
            }
        }
        __syncthreads();
    }

    const int rbase = row0 + wr * 64 + (lane >> 4) * 4;
    const int cbase = col0 + wc * 64 + (lane & 15);
    float bv[4];
#pragma unroll
    for (int n = 0; n < 4; n++) bv[n] = bias[cbase + n * 16];
#pragma unroll
    for (int m = 0; m < 4; m++)
#pragma unroll
        for (int n = 0; n < 4; n++)
#pragma unroll
            for (int r = 0; r < 4; r++) {
                float o = acc[m][n][r] + bv[n];
                if constexpr (RELU) o = fmaxf(o, 0.f);
                size_t off = (size_t)(rbase + m * 16 + r) * N + (cbase + n * 16);
                if constexpr (WF32) C[off] = o;
                if constexpr (NSO >= 1) {
                    u16 p0 = f2bf(o);
                    C0[off] = p0;
                    if constexpr (NSO >= 3) {
                        float r1 = o - bf2f(p0);
                        u16 p1 = f2bf(r1);
                        C1[off] = p1;
                        r1 -= bf2f(p1);
                        C2[off] = f2bf(r1);
                    }
                }
            }
}

// ---------------- weight transpose + split prepass ----------------
template<int NS>
__global__ __launch_bounds__(256)
void wsplit_kernel(const float* __restrict__ W, u16* __restrict__ T0,
                   u16* __restrict__ T1, u16* __restrict__ T2, int Kd, int N)
{
    __shared__ float t[32][33];
    const int tx = threadIdx.x & 31, ty = threadIdx.x >> 5;
    const int n0 = blockIdx.x * 32, k0 = blockIdx.y * 32;
#pragma unroll
    for (int r = 0; r < 4; r++)
        t[ty + r * 8][tx] = W[(size_t)(k0 + ty + r * 8) * N + n0 + tx];
    __syncthreads();
#pragma unroll
    for (int r = 0; r < 4; r++) {
        int n = n0 + ty + r * 8, k = k0 + tx;
        float v = t[tx][ty + r * 8];
        u16 h = f2bf(v);
        T0[(size_t)n * Kd + k] = h;
        if constexpr (NS >= 2) {
            float rr = v - bf2f(h);
            u16 m = f2bf(rr);
            T1[(size_t)n * Kd + k] = m;
            if constexpr (NS >= 3) { rr -= bf2f(m); T2[(size_t)n * Kd + k] = f2bf(rr); }
        }
    }
}

// ---------------- elementwise 3-plane split (x) ----------------
__global__ __launch_bounds__(256)
void esplit3_kernel(const float* __restrict__ src, u16* __restrict__ s0,
                    u16* __restrict__ s1, u16* __restrict__ s2)
{
    size_t i = (size_t)blockIdx.x * 256 + threadIdx.x;
    float4 v = ((const float4*)src)[i];
    float x[4] = {v.x, v.y, v.z, v.w};
    u16 h[4], m[4], l[4];
#pragma unroll
    for (int e = 0; e < 4; e++) {
        h[e] = f2bf(x[e]);
        float r1 = x[e] - bf2f(h[e]);
        m[e] = f2bf(r1);
        r1 -= bf2f(m[e]);
        l[e] = f2bf(r1);
    }
    ((ushort4*)s0)[i] = make_ushort4(h[0], h[1], h[2], h[3]);
    ((ushort4*)s1)[i] = make_ushort4(m[0], m[1], m[2], m[3]);
    ((ushort4*)s2)[i] = make_ushort4(l[0], l[1], l[2], l[3]);
}

__global__ void cnorm_kernel(const float* __restrict__ cb, float* __restrict__ cn)
{
    const int lane = threadIdx.x & 63;
    const int w = threadIdx.x >> 6;
    const int row = blockIdx.x * 4 + w;
    const float4 v = *(const float4*)(&cb[(size_t)row * D_ + lane * 4]);
    float s = v.x * v.x + v.y * v.y + v.z * v.z + v.w * v.w;
#pragma unroll
    for (int o = 32; o > 0; o >>= 1) s += __shfl_down(s, o, 64);
    if (lane == 0) cn[row] = s;
}

__global__ void loss_write_kernel(const float* __restrict__ loss_acc,
                                  float* __restrict__ out_loss)
{
    int q = threadIdx.x;
    if (q < Q_) out_loss[q] = loss_acc[q] * (1.0f / ((float)B_ * (float)D_));
}

// ---------------- launch ----------------
extern "C" void kernel_launch(void* const* d_in, const int* in_sizes, int n_in,
                              void* d_out, int out_size, void* d_ws, size_t ws_size,
                              hipStream_t stream)
{
    const float* x    = (const float*)d_in[0];
    const float* e_w0 = (const float*)d_in[1];
    const float* e_b0 = (const float*)d_in[2];
    const float* e_w1 = (const float*)d_in[3];
    const float* e_b1 = (const float*)d_in[4];
    const float* e_w2 = (const float*)d_in[5];
    const float* e_b2 = (const float*)d_in[6];
    const float* d_w0 = (const float*)d_in[7];
    const float* d_b0 = (const float*)d_in[8];
    const float* d_w1 = (const float*)d_in[9];
    const float* d_b1 = (const float*)d_in[10];
    const float* d_w2 = (const float*)d_in[11];
    const float* d_b2 = (const float*)d_in[12];
    const float* codebooks = (const float*)d_in[13];

    float* out = (float*)d_out;
    float* out_decoded = out;
    float* out_idx     = out + (size_t)B_ * IN_;
    float* out_loss    = out_idx + (size_t)B_ * Q_;

    char* w = (char*)d_ws;
    auto alloc = [&](size_t bytes) {
        char* r = w; w += (bytes + 255) & ~(size_t)255; return r;
    };
    u16* ew0t = (u16*)alloc((size_t)3 * IN_ * H0_ * 2);
    u16* ew1t = (u16*)alloc((size_t)3 * H0_ * H1_ * 2);
    u16* ew2t = (u16*)alloc((size_t)3 * H1_ * D_ * 2);
    u16* dw0t = (u16*)alloc((size_t)D_ * H1_ * 2);
    u16* dw1t = (u16*)alloc((size_t)H1_ * H0_ * 2);
    u16* dw2t = (u16*)alloc((size_t)H0_ * IN_ * 2);
    u16* cbF  = (u16*)alloc((size_t)3 * Q_ * K_ * D_ * 2);   // packed B planes
    u16* apF  = (u16*)alloc((size_t)3 * B_ * D_ * 2);        // packed A planes
    float* cnorm = (float*)alloc((size_t)Q_ * K_ * 4);
    float* loss  = (float*)alloc(64);
    float* zbuf  = (float*)alloc((size_t)B_ * D_ * 4);
    float* residb = (float*)alloc((size_t)B_ * D_ * 4);
    u64* winners = (u64*)alloc((size_t)B_ * 8);
    u16* qplane  = (u16*)alloc((size_t)B_ * D_ * 2);
    char* regX = alloc((size_t)3 * B_ * IN_ * 2);
    u16* xp0 = (u16*)regX;
    u16* xp1 = xp0 + (size_t)B_ * IN_;
    u16* xp2 = xp1 + (size_t)B_ * IN_;
    u16* h1p0 = (u16*)regX;                       // after G1 consumed
    u16* h1p1 = h1p0 + (size_t)B_ * H1_;
    u16* h1p2 = h1p1 + (size_t)B_ * H1_;
    u16* dh1p = h1p2 + (size_t)B_ * H1_;
    u16* dh0p = dh1p + (size_t)B_ * H1_;
    char* regH = alloc((size_t)3 * B_ * H0_ * 2);
    u16* h0p0 = (u16*)regH;
    u16* h0p1 = h0p0 + (size_t)B_ * H0_;
    u16* h0p2 = h0p1 + (size_t)B_ * H0_;

    const size_t ew0s = (size_t)IN_ * H0_, ew1s = (size_t)H0_ * H1_,
                 ew2s = (size_t)H1_ * D_, cbsz = (size_t)Q_ * K_ * D_;
    const size_t apsz = (size_t)B_ * D_;

    // ---- init + prepasses ----
    hipMemsetAsync(loss, 0, 64, stream);
    esplit3_kernel<<<(size_t)B_ * IN_ / 1024, 256, 0, stream>>>(x, xp0, xp1, xp2);
    cbpack_kernel<<<2048, 256, 0, stream>>>(
        codebooks, cbF, cbF + cbsz, cbF + 2 * cbsz);
    wsplit_kernel<3><<<dim3(H0_ / 32, IN_ / 32), 256, 0, stream>>>(
        e_w0, ew0t, ew0t + ew0s, ew0t + 2 * ew0s, IN_, H0_);
    wsplit_kernel<3><<<dim3(H1_ / 32, H0_ / 32), 256, 0, stream>>>(
        e_w1, ew1t, ew1t + ew1s, ew1t + 2 * ew1s, H0_, H1_);
    wsplit_kernel<3><<<dim3(D_ / 32, H1_ / 32), 256, 0, stream>>>(
        e_w2, ew2t, ew2t + ew2s, ew2t + 2 * ew2s, H1_, D_);
    wsplit_kernel<1><<<dim3(H1_ / 32, D_ / 32), 256, 0, stream>>>(
        d_w0, dw0t, nullptr, nullptr, D_, H1_);
    wsplit_kernel<1><<<dim3(H0_ / 32, H1_ / 32), 256, 0, stream>>>(
        d_w1, dw1t, nullptr, nullptr, H1_, H0_);
    wsplit_kernel<1><<<dim3(IN_ / 32, H0_ / 32), 256, 0, stream>>>(
        d_w2, dw2t, nullptr, nullptr, H0_, IN_);
    cnorm_kernel<<<(Q_ * K_) / 4, 256, 0, stream>>>(codebooks, cnorm);

    // ---- encoder ----
    gemm2<3, 3, 1, 3, 0><<<(H0_ / 128) * (B_ / 256), 512, 0, stream>>>(
        xp0, xp1, xp2, ew0t, ew0t + ew0s, ew0t + 2 * ew0s, e_b0,
        nullptr, h0p0, h0p1, h0p2, H0_, IN_);
    gemm_mfma<3, 3, 1, 3, 0><<<dim3(H1_ / 128, B_ / 128), 256, 0, stream>>>(
        h0p0, h0p1, h0p2, ew1t, ew1t + ew1s, ew1t + 2 * ew1s, e_b1,
        nullptr, h1p0, h1p1, h1p2, B_, H1_, H0_);
    gemm_mfma<3, 3, 0, 0, 1><<<dim3(D_ / 128, B_ / 128), 256, 0, stream>>>(
        h1p0, h1p1, h1p2, ew2t, ew2t + ew2s, ew2t + 2 * ew2s, e_b2,
        zbuf, nullptr, nullptr, nullptr, B_, D_, H1_);

    // ---- residual VQ: per-stage dist (full occupancy) + update ----
    apack_init<<<B_ / 16, 256, 0, stream>>>(zbuf, apF, apF + apsz, apF + 2 * apsz);
    for (int q = 0; q < Q_; q++) {
        dist_kernel<<<B_ / 32, 256, 0, stream>>>(
            apF, apF + apsz, apF + 2 * apsz,
            cbF, cbF + cbsz, cbF + 2 * cbsz,
            cnorm, winners, out_idx, q);
        vq_update<<<B_ / 16, 256, 0, stream>>>(
            winners, zbuf, codebooks, residb,
            apF, apF + apsz, apF + 2 * apsz, qplane, loss, q);
    }
    loss_write_kernel<<<1, 64, 0, stream>>>(loss, out_loss);

    // ---- decoder ----
    gemm_mfma<1, 1, 1, 1, 0><<<dim3(H1_ / 128, B_ / 128), 256, 0, stream>>>(
        qplane, nullptr, nullptr, dw0t, nullptr, nullptr, d_b0,
        nullptr, dh1p, nullptr, nullptr, B_, H1_, D_);
    gemm2<1, 1, 1, 1, 0><<<(H0_ / 128) * (B_ / 256), 512, 0, stream>>>(
        dh1p, nullptr, nullptr, dw1t, nullptr, nullptr, d_b1,
        nullptr, dh0p, nullptr, nullptr, H0_, H1_);
    gemm2<1, 1, 0, 0, 1><<<(IN_ / 128) * (B_ / 256), 512, 0, stream>>>(
        dh0p, nullptr, nullptr, dw2t, nullptr, nullptr, d_b2,
        out_decoded, nullptr, nullptr, nullptr, IN_, H0_);
}

// Round 17
// 1431.639 us; speedup vs baseline: 1.0674x; 1.0674x over previous
//
#include <hip/hip_runtime.h>
#include <stdint.h>

#define B_   8192
#define IN_  2048
#define H0_  1024
#define H1_  512
#define D_   256
#define Q_   8
#define K_   2048

typedef unsigned long long u64;
typedef unsigned short u16;
typedef __attribute__((ext_vector_type(8))) short bf16x8;
typedef __attribute__((ext_vector_type(4))) float f32x4;

__device__ __forceinline__ u16 f2bf(float x) {
    unsigned u = __float_as_uint(x);
    return (u16)((u + 0x7fffu + ((u >> 16) & 1u)) >> 16);
}
__device__ __forceinline__ float bf2f(u16 h) {
    return __uint_as_float((unsigned)h << 16);
}
__device__ __forceinline__ void gload_lds16(const void* g, void* l) {
    __builtin_amdgcn_global_load_lds(
        (const __attribute__((address_space(1))) void*)g,
        (__attribute__((address_space(3))) void*)l, 16, 0, 0);
}
__device__ __forceinline__ unsigned fkey(float f) {
    unsigned u = __float_as_uint(f);
    return (u & 0x80000000u) ? ~u : (u | 0x80000000u);
}

#define MFMA_BF16 __builtin_amdgcn_mfma_f32_16x16x32_bf16

// =====================================================================
// cbpack: codebooks -> bf16x3 planes in MFMA fragment order.
// group g = q*1024 + cg*8 + k; lane l: col cg*16+(l&15), dims k*32+(l>>4)*8.
// =====================================================================
__global__ __launch_bounds__(256)
void cbpack_kernel(const float* __restrict__ cb, u16* __restrict__ f0,
                   u16* __restrict__ f1, u16* __restrict__ f2)
{
    const int g    = blockIdx.x * 4 + (threadIdx.x >> 6);  // 0..8191
    const int lane = threadIdx.x & 63;
    const int q = g >> 10, rem = g & 1023, cg = rem >> 3, k = rem & 7;
    const int col = cg * 16 + (lane & 15);
    const int d0  = k * 32 + (lane >> 4) * 8;
    const float* src = cb + ((size_t)q * K_ + col) * D_ + d0;
    float4 va = *(const float4*)src, vb = *(const float4*)(src + 4);
    float xs[8] = {va.x, va.y, va.z, va.w, vb.x, vb.y, vb.z, vb.w};
    u16 h[8], m[8], l8[8];
#pragma unroll
    for (int e = 0; e < 8; e++) {
        h[e] = f2bf(xs[e]);
        float r1 = xs[e] - bf2f(h[e]);
        m[e] = f2bf(r1);
        r1 -= bf2f(m[e]);
        l8[e] = f2bf(r1);
    }
    const size_t off = ((size_t)g * 64 + lane) * 8;
    *(ushort4*)(f0 + off)     = make_ushort4(h[0], h[1], h[2], h[3]);
    *(ushort4*)(f0 + off + 4) = make_ushort4(h[4], h[5], h[6], h[7]);
    *(ushort4*)(f1 + off)     = make_ushort4(m[0], m[1], m[2], m[3]);
    *(ushort4*)(f1 + off + 4) = make_ushort4(m[4], m[5], m[6], m[7]);
    *(ushort4*)(f2 + off)     = make_ushort4(l8[0], l8[1], l8[2], l8[3]);
    *(ushort4*)(f2 + off + 4) = make_ushort4(l8[4], l8[5], l8[6], l8[7]);
}

// ---- shared helper: write one 8-dim chunk of row into packed A-planes ----
__device__ __forceinline__ void apack_write(u16* ap0, u16* ap1, u16* ap2,
                                            int row, int kc, const float* d)
{
    int ga = (row >> 4) * 8 + (kc >> 2);
    int lane_in = (row & 15) + (kc & 3) * 16;
    size_t o = ((size_t)ga * 64 + lane_in) * 8;
    u16 h[8], m[8], l[8];
#pragma unroll
    for (int e = 0; e < 8; e++) {
        h[e] = f2bf(d[e]);
        float r1 = d[e] - bf2f(h[e]);
        m[e] = f2bf(r1);
        r1 -= bf2f(m[e]);
        l[e] = f2bf(r1);
    }
    *(ushort4*)(ap0 + o)     = make_ushort4(h[0], h[1], h[2], h[3]);
    *(ushort4*)(ap0 + o + 4) = make_ushort4(h[4], h[5], h[6], h[7]);
    *(ushort4*)(ap1 + o)     = make_ushort4(m[0], m[1], m[2], m[3]);
    *(ushort4*)(ap1 + o + 4) = make_ushort4(m[4], m[5], m[6], m[7]);
    *(ushort4*)(ap2 + o)     = make_ushort4(l[0], l[1], l[2], l[3]);
    *(ushort4*)(ap2 + o + 4) = make_ushort4(l[4], l[5], l[6], l[7]);
}

// ---- initial A-plane pack from z ----
__global__ __launch_bounds__(256)
void apack_init(const float* __restrict__ z, u16* __restrict__ ap0,
                u16* __restrict__ ap1, u16* __restrict__ ap2)
{
    const int row = blockIdx.x * 16 + (threadIdx.x >> 4);
    const int dc  = threadIdx.x & 15;
#pragma unroll
    for (int j = 0; j < 2; j++) {
        int kc = dc * 2 + j;
        float d[8];
        const float* src = z + (size_t)row * D_ + kc * 8;
        float4 v0 = *(const float4*)src, v1 = *(const float4*)(src + 4);
        d[0] = v0.x; d[1] = v0.y; d[2] = v0.z; d[3] = v0.w;
        d[4] = v1.x; d[5] = v1.y; d[6] = v1.z; d[7] = v1.w;
        apack_write(ap0, ap1, ap2, row, kc, d);
    }
}

// =====================================================================
// dist_kernel v2: LDS-free, mf=2 row reuse (R14's proven 204-VGPR body),
// 512 blocks (2/CU, 8 waves/CU) x 256 thr. Block = (32 rows, 1024-col
// half); wave = 32 rows x 256 cols (4 groups of 64). Per k-step: 6
// coalesced a-loads + batched 12 b-loads -> 48 MFMA. Per-row argmin via
// packed-u64 atomicMin (order-independent; indices bit-identical).
// =====================================================================
__global__ __launch_bounds__(256)
void dist_kernel(const u16* __restrict__ ap0, const u16* __restrict__ ap1,
                 const u16* __restrict__ ap2,
                 const u16* __restrict__ cbF0, const u16* __restrict__ cbF1,
                 const u16* __restrict__ cbF2,
                 const float* __restrict__ cnorm,
                 u64* __restrict__ best, int q)
{
    const int tid  = threadIdx.x;
    const int lane = tid & 63;
    const int wv   = tid >> 6;                 // 0..3
    const int rb   = blockIdx.x >> 1;          // 32-row block
    const int chb  = blockIdx.x & 1;           // 1024-col half
    const int row0 = rb * 32;
    const int ga0  = rb * 16;                  // apF group base ((row0>>4)*8)
    const float* cnq = cnorm + (size_t)q * K_;

    u64 best4[2][4];
#pragma unroll
    for (int mf = 0; mf < 2; mf++)
#pragma unroll
        for (int r = 0; r < 4; r++) best4[mf][r] = ~0ull;

    for (int g = 0; g < 4; g++) {
        const int cg0 = chb * 64 + wv * 16 + g * 4;   // 16-col group base
        f32x4 acc[2][4];
#pragma unroll
        for (int mf = 0; mf < 2; mf++)
#pragma unroll
            for (int n = 0; n < 4; n++) acc[mf][n] = (f32x4){0.f, 0.f, 0.f, 0.f};

#pragma unroll
        for (int k = 0; k < 8; k++) {
            bf16x8 a0[2], a1[2], a2[2];
#pragma unroll
            for (int mf = 0; mf < 2; mf++) {
                size_t fa = (((size_t)(ga0 + mf * 8 + k)) * 64 + lane) * 8;
                a0[mf] = *(const bf16x8*)(ap0 + fa);
                a1[mf] = *(const bf16x8*)(ap1 + fa);
                a2[mf] = *(const bf16x8*)(ap2 + fa);
            }
            bf16x8 b0[4], b1[4], b2[4];
#pragma unroll
            for (int n = 0; n < 4; n++) {
                size_t fb = (((size_t)(q << 10) + (cg0 + n) * 8 + k) << 9)
                            + lane * 8;
                b0[n] = *(const bf16x8*)(cbF0 + fb);
                b1[n] = *(const bf16x8*)(cbF1 + fb);
                b2[n] = *(const bf16x8*)(cbF2 + fb);
            }
#pragma unroll
            for (int n = 0; n < 4; n++) {
#pragma unroll
                for (int mf = 0; mf < 2; mf++) {
                    acc[mf][n] = MFMA_BF16(a0[mf], b0[n], acc[mf][n], 0, 0, 0);
                    acc[mf][n] = MFMA_BF16(a1[mf], b0[n], acc[mf][n], 0, 0, 0);
                    acc[mf][n] = MFMA_BF16(a0[mf], b1[n], acc[mf][n], 0, 0, 0);
                    acc[mf][n] = MFMA_BF16(a1[mf], b1[n], acc[mf][n], 0, 0, 0);
                    acc[mf][n] = MFMA_BF16(a2[mf], b0[n], acc[mf][n], 0, 0, 0);
                    acc[mf][n] = MFMA_BF16(a0[mf], b2[n], acc[mf][n], 0, 0, 0);
                }
            }
        }
#pragma unroll
        for (int n = 0; n < 4; n++) {
            int col = (cg0 + n) * 16 + (lane & 15);
            float cn = cnq[col];
#pragma unroll
            for (int mf = 0; mf < 2; mf++)
#pragma unroll
                for (int r = 0; r < 4; r++) {
                    float d = cn - 2.0f * acc[mf][n][r];
                    u64 p = ((u64)fkey(d) << 32) | (unsigned)col;
                    if (p < best4[mf][r]) best4[mf][r] = p;
                }
        }
    }

    // fold across the 16 cols held by lanes, then global atomicMin per row
#pragma unroll
    for (int mf = 0; mf < 2; mf++)
#pragma unroll
        for (int r = 0; r < 4; r++) {
            u64 p = best4[mf][r];
#pragma unroll
            for (int msk = 1; msk <= 8; msk <<= 1) {
                u64 o = __shfl_xor(p, msk, 64);
                if (o < p) p = o;
            }
            if ((lane & 15) == 0)
                atomicMin(&best[row0 + mf * 16 + (lane >> 4) * 4 + r], p);
        }
}

// =====================================================================
// vq_update: read winner, reset best, fp32 residual update, loss, and
// write next stage's packed A-planes (or qplane at q==7).
// grid B_/16, 256 threads; thread = (row, 16-dim slice).
// =====================================================================
__global__ __launch_bounds__(256)
void vq_update(u64* __restrict__ best, const float* __restrict__ z,
               const float* __restrict__ CB, float* __restrict__ resid,
               u16* __restrict__ ap0, u16* __restrict__ ap1,
               u16* __restrict__ ap2, u16* __restrict__ qplane,
               float* __restrict__ out_idx, float* __restrict__ loss_acc,
               int q)
{
    const int tid  = threadIdx.x;
    const int lane = tid & 63;
    const int row  = blockIdx.x * 16 + (tid >> 4);
    const int dc   = tid & 15;
    const u64 wv = best[row];
    const unsigned idx = (unsigned)(wv & 0xffffffffu);
    __syncthreads();                       // all reads done before reset
    if (dc == 0) {
        best[row] = ~0ull;                 // re-arm for next stage
        out_idx[(size_t)row * Q_ + q] = (float)idx;
    }

    const float* rsrc = (q == 0) ? z : resid;
    const size_t off = (size_t)row * D_ + dc * 16;
    const float* cw = CB + ((size_t)q * K_ + idx) * D_ + dc * 16;

    float d[16];
    float lsum = 0.f;
#pragma unroll
    for (int e = 0; e < 16; e += 4) {
        float4 rv = *(const float4*)(rsrc + off + e);
        float4 cv = *(const float4*)(cw + e);
        d[e]     = rv.x - cv.x;
        d[e + 1] = rv.y - cv.y;
        d[e + 2] = rv.z - cv.z;
        d[e + 3] = rv.w - cv.w;
        lsum += d[e] * d[e] + d[e+1] * d[e+1] + d[e+2] * d[e+2] + d[e+3] * d[e+3];
    }

    if (q < Q_ - 1) {
#pragma unroll
        for (int e = 0; e < 16; e += 4)
            *(float4*)(resid + off + e) = make_float4(d[e], d[e+1], d[e+2], d[e+3]);
#pragma unroll
        for (int j = 0; j < 2; j++)
            apack_write(ap0, ap1, ap2, row, dc * 2 + j, d + j * 8);
    } else {
#pragma unroll
        for (int e = 0; e < 16; e += 8) {
            float4 z0 = *(const float4*)(z + off + e);
            float4 z1 = *(const float4*)(z + off + e + 4);
            *(ushort4*)(qplane + off + e) = make_ushort4(
                f2bf(z0.x - d[e]),     f2bf(z0.y - d[e + 1]),
                f2bf(z0.z - d[e + 2]), f2bf(z0.w - d[e + 3]));
            *(ushort4*)(qplane + off + e + 4) = make_ushort4(
                f2bf(z1.x - d[e + 4]), f2bf(z1.y - d[e + 5]),
                f2bf(z1.z - d[e + 6]), f2bf(z1.w - d[e + 7]));
        }
    }

#pragma unroll
    for (int o = 32; o > 0; o >>= 1) lsum += __shfl_down(lsum, o, 64);
    if (lane == 0) atomicAdd(&loss_acc[q], lsum);
}

// =====================================================================
// gemm2: 256x128 tile, 512 threads, 2-phase prefetch, XCD swizzle
// =====================================================================
template<int NSA, int NSB, int RELU, int NSO, int WF32>
__global__ __launch_bounds__(512)
void gemm2(const u16* __restrict__ A0, const u16* __restrict__ A1,
           const u16* __restrict__ A2,
           const u16* __restrict__ B0, const u16* __restrict__ B1,
           const u16* __restrict__ B2,
           const float* __restrict__ bias,
           float* __restrict__ C,
           u16* __restrict__ C0, u16* __restrict__ C1, u16* __restrict__ C2,
           int N, int Kd)
{
    constexpr int HALF = NSA * 16384 + NSB * 8192;
    __shared__ __align__(16) char smem[2 * HALF];
    const int tid  = threadIdx.x;
    const int lane = tid & 63;
    const int wid  = tid >> 6;
    const int wr   = wid >> 1, wc = wid & 1;

    const int nwg  = gridDim.x;
    const int orig = blockIdx.x;
    const int xcd  = orig & 7;
    const int q8 = nwg >> 3, r8 = nwg & 7;
    const int wgid = (xcd < r8 ? xcd * (q8 + 1)
                               : r8 * (q8 + 1) + (xcd - r8) * q8) + (orig >> 3);
    const int gx = N >> 7;
    const int bx = wgid % gx;
    const int by = wgid / gx;
    const int row0 = by * 256;
    const int col0 = bx * 128;

    const u16* asrc[3][2];
    const u16* bsrc[3];
#pragma unroll
    for (int h = 0; h < 2; h++) {
        int ch = h * 512 + tid;
        int r  = ch >> 2;
        int kc = (ch & 3) ^ ((r >> 1) & 3);
        size_t off = (size_t)(row0 + r) * Kd + kc * 8;
        asrc[0][h] = A0 + off;
        if constexpr (NSA >= 3) { asrc[1][h] = A1 + off; asrc[2][h] = A2 + off; }
    }
    {
        int r  = tid >> 2;
        int kc = (tid & 3) ^ ((r >> 1) & 3);
        size_t off = (size_t)(col0 + r) * Kd + kc * 8;
        bsrc[0] = B0 + off;
        if constexpr (NSB >= 3) { bsrc[1] = B1 + off; bsrc[2] = B2 + off; }
    }

    auto stage = [&](int c) {
        char* base = smem + c * HALF;
#pragma unroll
        for (int s = 0; s < NSA; s++)
#pragma unroll
            for (int h = 0; h < 2; h++) {
                gload_lds16(asrc[s][h], base + s * 16384 + (h * 512 + tid) * 16);
                asrc[s][h] += 32;
            }
#pragma unroll
        for (int s = 0; s < NSB; s++) {
            gload_lds16(bsrc[s], base + NSA * 16384 + s * 8192 + tid * 16);
            bsrc[s] += 32;
        }
    };

    f32x4 acc[4][4];
#pragma unroll
    for (int m = 0; m < 4; m++)
#pragma unroll
        for (int n = 0; n < 4; n++) acc[m][n] = (f32x4){0.f, 0.f, 0.f, 0.f};

    const unsigned fro = (unsigned)((lane & 15) * 64
        + (((lane >> 4) ^ (((lane & 15) >> 1) & 3)) * 16));

    const int nt = Kd >> 5;
    int cur = 0;
    stage(0);
    __syncthreads();

    for (int t = 0; t < nt; t++) {
        if (t + 1 < nt) stage(cur ^ 1);
        const char* base = smem + cur * HALF;
        bf16x8 bfr[4][3];
#pragma unroll
        for (int n = 0; n < 4; n++)
#pragma unroll
            for (int s = 0; s < NSB; s++)
                bfr[n][s] = *(const bf16x8*)(base + NSA * 16384 + s * 8192
                                             + (wc * 64 + n * 16) * 64 + fro);
#pragma unroll
        for (int m = 0; m < 4; m++) {
            bf16x8 af[3];
#pragma unroll
            for (int s = 0; s < NSA; s++)
                af[s] = *(const bf16x8*)(base + s * 16384
                                         + (wr * 64 + m * 16) * 64 + fro);
#pragma unroll
            for (int n = 0; n < 4; n++) {
                acc[m][n] = MFMA_BF16(af[0], bfr[n][0], acc[m][n], 0, 0, 0);
                if constexpr (NSA >= 3 && NSB >= 3) {
                    acc[m][n] = MFMA_BF16(af[1], bfr[n][0], acc[m][n], 0, 0, 0);
                    acc[m][n] = MFMA_BF16(af[0], bfr[n][1], acc[m][n], 0, 0, 0);
                    acc[m][n] = MFMA_BF16(af[1], bfr[n][1], acc[m][n], 0, 0, 0);
                    acc[m][n] = MFMA_BF16(af[2], bfr[n][0], acc[m][n], 0, 0, 0);
                    acc[m][n] = MFMA_BF16(af[0], bfr[n][2], acc[m][n], 0, 0, 0);
                }
            }
        }
        __syncthreads();
        cur ^= 1;
    }

    const int rbase = row0 + wr * 64 + (lane >> 4) * 4;
    const int cbase = col0 + wc * 64 + (lane & 15);
    float bv[4];
#pragma unroll
    for (int n = 0; n < 4; n++) bv[n] = bias[cbase + n * 16];
#pragma unroll
    for (int m = 0; m < 4; m++)
#pragma unroll
        for (int n = 0; n < 4; n++)
#pragma unroll
            for (int r = 0; r < 4; r++) {
                float o = acc[m][n][r] + bv[n];
                if constexpr (RELU) o = fmaxf(o, 0.f);
                size_t off = (size_t)(rbase + m * 16 + r) * N + (cbase + n * 16);
                if constexpr (WF32) C[off] = o;
                if constexpr (NSO >= 1) {
                    u16 p0 = f2bf(o);
                    C0[off] = p0;
                    if constexpr (NSO >= 3) {
                        float r1 = o - bf2f(p0);
                        u16 p1 = f2bf(r1);
                        C1[off] = p1;
                        r1 -= bf2f(p1);
                        C2[off] = f2bf(r1);
                    }
                }
            }
}

// =====================================================================
// gemm_mfma: 128x128 / 4-wave kernel (small-N GEMMs: enc G2/G3, dec1)
// =====================================================================
template<int NSA, int NSB, int RELU, int NSO, int WF32>
__global__ __launch_bounds__(256)
void gemm_mfma(const u16* __restrict__ A0, const u16* __restrict__ A1,
               const u16* __restrict__ A2,
               const u16* __restrict__ B0, const u16* __restrict__ B1,
               const u16* __restrict__ B2,
               const float* __restrict__ bias,
               float* __restrict__ C,
               u16* __restrict__ C0, u16* __restrict__ C1, u16* __restrict__ C2,
               int M, int N, int Kd)
{
    constexpr int NP = NSA + NSB;
    __shared__ __align__(16) char smem[NP * 8192];
    const int tid  = threadIdx.x;
    const int lane = tid & 63;
    const int wid  = tid >> 6;
    const int wr   = wid >> 1, wc = wid & 1;
    const int row0 = blockIdx.y * 128;
    const int col0 = blockIdx.x * 128;

    const u16* asrc[3][2];
    const u16* bsrc[3][2];
#pragma unroll
    for (int h = 0; h < 2; h++) {
        int ch = h * 256 + tid;
        int r  = ch >> 2;
        int kc = (ch & 3) ^ ((r >> 1) & 3);
        size_t aoff = (size_t)(row0 + r) * Kd + kc * 8;
        size_t boff = (size_t)(col0 + r) * Kd + kc * 8;
        asrc[0][h] = A0 + aoff;
        if constexpr (NSA >= 3) { asrc[1][h] = A1 + aoff; asrc[2][h] = A2 + aoff; }
        bsrc[0][h] = B0 + boff;
        if constexpr (NSB >= 3) { bsrc[1][h] = B1 + boff; bsrc[2][h] = B2 + boff; }
    }

    f32x4 acc[4][4];
#pragma unroll
    for (int m = 0; m < 4; m++)
#pragma unroll
        for (int n = 0; n < 4; n++) acc[m][n] = (f32x4){0.f, 0.f, 0.f, 0.f};

    const unsigned fro = (unsigned)((lane & 15) * 64
        + (((lane >> 4) ^ (((lane & 15) >> 1) & 3)) * 16));

    for (int k0 = 0; k0 < Kd; k0 += 32) {
#pragma unroll
        for (int s = 0; s < NSA; s++)
#pragma unroll
            for (int h = 0; h < 2; h++) {
                gload_lds16(asrc[s][h], smem + s * 8192 + (h * 256 + tid) * 16);
                asrc[s][h] += 32;
            }
#pragma unroll
        for (int s = 0; s < NSB; s++)
#pragma unroll
            for (int h = 0; h < 2; h++) {
                gload_lds16(bsrc[s][h],
                            smem + (NSA + s) * 8192 + (h * 256 + tid) * 16);
                bsrc[s][h] += 32;
            }
        __syncthreads();

        bf16x8 bfr[4][3];
#pragma unroll
        for (int n = 0; n < 4; n++)
#pragma unroll
            for (int s = 0; s < NSB; s++)
                bfr[n][s] = *(const bf16x8*)(smem + (NSA + s) * 8192
                                             + (wc * 64 + n * 16) * 64 + fro);
#pragma unroll
        for (int m = 0; m < 4; m++) {
            bf16x8 af[3];
#pragma unroll
            for (int s = 0; s < NSA; s++)
                af[s] = *(const bf16x8*)(smem + s * 8192
                                         + (wr * 64 + m * 16) * 64 + fro);
#pragma unroll
            for (int n = 0; n < 4; n++) {
                acc[m][n] = MFMA_BF16(af[0], bfr[n][0], acc[m][n], 0, 0, 0);
                if constexpr (NSA >= 3 && NSB >= 3) {
                    acc[m][n] = MFMA_BF16(af[1], bfr[n][0], acc[m][n], 0, 0, 0);
                    acc[m][n] = MFMA_BF16(af[0], bfr[n][1], acc[m][n], 0, 0, 0);
                    acc[m][n] = MFMA_BF16(af[1], bfr[n][1], acc[m][n], 0, 0, 0);
                    acc[m][n] = MFMA_BF16(af[2], bfr[n][0], acc[m][n], 0, 0, 0);
                    acc[m][n] = MFMA_BF16(af[0], bfr[n][2], acc[m][n], 0, 0, 0);
                }
            }
        }
        __syncthreads();
    }

    const int rbase = row0 + wr * 64 + (lane >> 4) * 4;
    const int cbase = col0 + wc * 64 + (lane & 15);
    float bv[4];
#pragma unroll
    for (int n = 0; n < 4; n++) bv[n] = bias[cbase + n * 16];
#pragma unroll
    for (int m = 0; m < 4; m++)
#pragma unroll
        for (int n = 0; n < 4; n++)
#pragma unroll
            for (int r = 0; r < 4; r++) {
                float o = acc[m][n][r] + bv[n];
                if constexpr (RELU) o = fmaxf(o, 0.f);
                size_t off = (size_t)(rbase + m * 16 + r) * N + (cbase + n * 16);
                if constexpr (WF32) C[off] = o;
                if constexpr (NSO >= 1) {
                    u16 p0 = f2bf(o);
                    C0[off] = p0;
                    if constexpr (NSO >= 3) {
                        float r1 = o - bf2f(p0);
                        u16 p1 = f2bf(r1);
                        C1[off] = p1;
                        r1 -= bf2f(p1);
                        C2[off] = f2bf(r1);
                    }
                }
            }
}

// ---------------- weight transpose + split prepass ----------------
template<int NS>
__global__ __launch_bounds__(256)
void wsplit_kernel(const float* __restrict__ W, u16* __restrict__ T0,
                   u16* __restrict__ T1, u16* __restrict__ T2, int Kd, int N)
{
    __shared__ float t[32][33];
    const int tx = threadIdx.x & 31, ty = threadIdx.x >> 5;
    const int n0 = blockIdx.x * 32, k0 = blockIdx.y * 32;
#pragma unroll
    for (int r = 0; r < 4; r++)
        t[ty + r * 8][tx] = W[(size_t)(k0 + ty + r * 8) * N + n0 + tx];
    __syncthreads();
#pragma unroll
    for (int r = 0; r < 4; r++) {
        int n = n0 + ty + r * 8, k = k0 + tx;
        float v = t[tx][ty + r * 8];
        u16 h = f2bf(v);
        T0[(size_t)n * Kd + k] = h;
        if constexpr (NS >= 2) {
            float rr = v - bf2f(h);
            u16 m = f2bf(rr);
            T1[(size_t)n * Kd + k] = m;
            if constexpr (NS >= 3) { rr -= bf2f(m); T2[(size_t)n * Kd + k] = f2bf(rr); }
        }
    }
}

// ---------------- elementwise 3-plane split (x) ----------------
__global__ __launch_bounds__(256)
void esplit3_kernel(const float* __restrict__ src, u16* __restrict__ s0,
                    u16* __restrict__ s1, u16* __restrict__ s2)
{
    size_t i = (size_t)blockIdx.x * 256 + threadIdx.x;
    float4 v = ((const float4*)src)[i];
    float x[4] = {v.x, v.y, v.z, v.w};
    u16 h[4], m[4], l[4];
#pragma unroll
    for (int e = 0; e < 4; e++) {
        h[e] = f2bf(x[e]);
        float r1 = x[e] - bf2f(h[e]);
        m[e] = f2bf(r1);
        r1 -= bf2f(m[e]);
        l[e] = f2bf(r1);
    }
    ((ushort4*)s0)[i] = make_ushort4(h[0], h[1], h[2], h[3]);
    ((ushort4*)s1)[i] = make_ushort4(m[0], m[1], m[2], m[3]);
    ((ushort4*)s2)[i] = make_ushort4(l[0], l[1], l[2], l[3]);
}

__global__ void cnorm_kernel(const float* __restrict__ cb, float* __restrict__ cn)
{
    const int lane = threadIdx.x & 63;
    const int w = threadIdx.x >> 6;
    const int row = blockIdx.x * 4 + w;
    const float4 v = *(const float4*)(&cb[(size_t)row * D_ + lane * 4]);
    float s = v.x * v.x + v.y * v.y + v.z * v.z + v.w * v.w;
#pragma unroll
    for (int o = 32; o > 0; o >>= 1) s += __shfl_down(s, o, 64);
    if (lane == 0) cn[row] = s;
}

__global__ void loss_write_kernel(const float* __restrict__ loss_acc,
                                  float* __restrict__ out_loss)
{
    int q = threadIdx.x;
    if (q < Q_) out_loss[q] = loss_acc[q] * (1.0f / ((float)B_ * (float)D_));
}

// ---------------- launch ----------------
extern "C" void kernel_launch(void* const* d_in, const int* in_sizes, int n_in,
                              void* d_out, int out_size, void* d_ws, size_t ws_size,
                              hipStream_t stream)
{
    const float* x    = (const float*)d_in[0];
    const float* e_w0 = (const float*)d_in[1];
    const float* e_b0 = (const float*)d_in[2];
    const float* e_w1 = (const float*)d_in[3];
    const float* e_b1 = (const float*)d_in[4];
    const float* e_w2 = (const float*)d_in[5];
    const float* e_b2 = (const float*)d_in[6];
    const float* d_w0 = (const float*)d_in[7];
    const float* d_b0 = (const float*)d_in[8];
    const float* d_w1 = (const float*)d_in[9];
    const float* d_b1 = (const float*)d_in[10];
    const float* d_w2 = (const float*)d_in[11];
    const float* d_b2 = (const float*)d_in[12];
    const float* codebooks = (const float*)d_in[13];

    float* out = (float*)d_out;
    float* out_decoded = out;
    float* out_idx     = out + (size_t)B_ * IN_;
    float* out_loss    = out_idx + (size_t)B_ * Q_;

    char* w = (char*)d_ws;
    auto alloc = [&](size_t bytes) {
        char* r = w; w += (bytes + 255) & ~(size_t)255; return r;
    };
    u16* ew0t = (u16*)alloc((size_t)3 * IN_ * H0_ * 2);
    u16* ew1t = (u16*)alloc((size_t)3 * H0_ * H1_ * 2);
    u16* ew2t = (u16*)alloc((size_t)3 * H1_ * D_ * 2);
    u16* dw0t = (u16*)alloc((size_t)D_ * H1_ * 2);
    u16* dw1t = (u16*)alloc((size_t)H1_ * H0_ * 2);
    u16* dw2t = (u16*)alloc((size_t)H0_ * IN_ * 2);
    u16* cbF  = (u16*)alloc((size_t)3 * Q_ * K_ * D_ * 2);   // packed B planes
    u16* apF  = (u16*)alloc((size_t)3 * B_ * D_ * 2);        // packed A planes
    float* cnorm = (float*)alloc((size_t)Q_ * K_ * 4);
    float* loss  = (float*)alloc(64);
    float* zbuf  = (float*)alloc((size_t)B_ * D_ * 4);
    float* residb = (float*)alloc((size_t)B_ * D_ * 4);
    u64* best = (u64*)alloc((size_t)B_ * 8);
    u16* qplane  = (u16*)alloc((size_t)B_ * D_ * 2);
    char* regX = alloc((size_t)3 * B_ * IN_ * 2);
    u16* xp0 = (u16*)regX;
    u16* xp1 = xp0 + (size_t)B_ * IN_;
    u16* xp2 = xp1 + (size_t)B_ * IN_;
    u16* h1p0 = (u16*)regX;                       // after G1 consumed
    u16* h1p1 = h1p0 + (size_t)B_ * H1_;
    u16* h1p2 = h1p1 + (size_t)B_ * H1_;
    u16* dh1p = h1p2 + (size_t)B_ * H1_;
    u16* dh0p = dh1p + (size_t)B_ * H1_;
    char* regH = alloc((size_t)3 * B_ * H0_ * 2);
    u16* h0p0 = (u16*)regH;
    u16* h0p1 = h0p0 + (size_t)B_ * H0_;
    u16* h0p2 = h0p1 + (size_t)B_ * H0_;

    const size_t ew0s = (size_t)IN_ * H0_, ew1s = (size_t)H0_ * H1_,
                 ew2s = (size_t)H1_ * D_, cbsz = (size_t)Q_ * K_ * D_;
    const size_t apsz = (size_t)B_ * D_;

    // ---- init + prepasses ----
    hipMemsetAsync(loss, 0, 64, stream);
    hipMemsetAsync(best, 0xFF, (size_t)B_ * 8, stream);
    esplit3_kernel<<<(size_t)B_ * IN_ / 1024, 256, 0, stream>>>(x, xp0, xp1, xp2);
    cbpack_kernel<<<2048, 256, 0, stream>>>(
        codebooks, cbF, cbF + cbsz, cbF + 2 * cbsz);
    wsplit_kernel<3><<<dim3(H0_ / 32, IN_ / 32), 256, 0, stream>>>(
        e_w0, ew0t, ew0t + ew0s, ew0t + 2 * ew0s, IN_, H0_);
    wsplit_kernel<3><<<dim3(H1_ / 32, H0_ / 32), 256, 0, stream>>>(
        e_w1, ew1t, ew1t + ew1s, ew1t + 2 * ew1s, H0_, H1_);
    wsplit_kernel<3><<<dim3(D_ / 32, H1_ / 32), 256, 0, stream>>>(
        e_w2, ew2t, ew2t + ew2s, ew2t + 2 * ew2s, H1_, D_);
    wsplit_kernel<1><<<dim3(H1_ / 32, D_ / 32), 256, 0, stream>>>(
        d_w0, dw0t, nullptr, nullptr, D_, H1_);
    wsplit_kernel<1><<<dim3(H0_ / 32, H1_ / 32), 256, 0, stream>>>(
        d_w1, dw1t, nullptr, nullptr, H1_, H0_);
    wsplit_kernel<1><<<dim3(IN_ / 32, H0_ / 32), 256, 0, stream>>>(
        d_w2, dw2t, nullptr, nullptr, H0_, IN_);
    cnorm_kernel<<<(Q_ * K_) / 4, 256, 0, stream>>>(codebooks, cnorm);

    // ---- encoder ----
    gemm2<3, 3, 1, 3, 0><<<(H0_ / 128) * (B_ / 256), 512, 0, stream>>>(
        xp0, xp1, xp2, ew0t, ew0t + ew0s, ew0t + 2 * ew0s, e_b0,
        nullptr, h0p0, h0p1, h0p2, H0_, IN_);
    gemm_mfma<3, 3, 1, 3, 0><<<dim3(H1_ / 128, B_ / 128), 256, 0, stream>>>(
        h0p0, h0p1, h0p2, ew1t, ew1t + ew1s, ew1t + 2 * ew1s, e_b1,
        nullptr, h1p0, h1p1, h1p2, B_, H1_, H0_);
    gemm_mfma<3, 3, 0, 0, 1><<<dim3(D_ / 128, B_ / 128), 256, 0, stream>>>(
        h1p0, h1p1, h1p2, ew2t, ew2t + ew2s, ew2t + 2 * ew2s, e_b2,
        zbuf, nullptr, nullptr, nullptr, B_, D_, H1_);

    // ---- residual VQ: per-stage dist (2 blocks/CU) + update ----
    apack_init<<<B_ / 16, 256, 0, stream>>>(zbuf, apF, apF + apsz, apF + 2 * apsz);
    for (int q = 0; q < Q_; q++) {
        dist_kernel<<<(B_ / 32) * 2, 256, 0, stream>>>(
            apF, apF + apsz, apF + 2 * apsz,
            cbF, cbF + cbsz, cbF + 2 * cbsz,
            cnorm, best, q);
        vq_update<<<B_ / 16, 256, 0, stream>>>(
            best, zbuf, codebooks, residb,
            apF, apF + apsz, apF + 2 * apsz, qplane, out_idx, loss, q);
    }
    loss_write_kernel<<<1, 64, 0, stream>>>(loss, out_loss);

    // ---- decoder ----
    gemm_mfma<1, 1, 1, 1, 0><<<dim3(H1_ / 128, B_ / 128), 256, 0, stream>>>(
        qplane, nullptr, nullptr, dw0t, nullptr, nullptr, d_b0,
        nullptr, dh1p, nullptr, nullptr, B_, H1_, D_);
    gemm2<1, 1, 1, 1, 0><<<(H0_ / 128) * (B_ / 256), 512, 0, stream>>>(
        dh1p, nullptr, nullptr, dw1t, nullptr, nullptr, d_b1,
        nullptr, dh0p, nullptr, nullptr, H0_, H1_);
    gemm2<1, 1, 0, 0, 1><<<(IN_ / 128) * (B_ / 256), 512, 0, stream>>>(
        dh0p, nullptr, nullptr, dw2t, nullptr, nullptr, d_b2,
        out_decoded, nullptr, nullptr, nullptr, IN_, H0_);
}

// Round 18
// 1358.339 us; speedup vs baseline: 1.1250x; 1.0540x over previous
//
#include <hip/hip_runtime.h>
#include <stdint.h>

#define B_   8192
#define IN_  2048
#define H0_  1024
#define H1_  512
#define D_   256
#define Q_   8
#define K_   2048

typedef unsigned long long u64;
typedef unsigned short u16;
typedef __attribute__((ext_vector_type(8))) short bf16x8;
typedef __attribute__((ext_vector_type(4))) float f32x4;

__device__ __forceinline__ u16 f2bf(float x) {
    unsigned u = __float_as_uint(x);
    return (u16)((u + 0x7fffu + ((u >> 16) & 1u)) >> 16);
}
__device__ __forceinline__ float bf2f(u16 h) {
    return __uint_as_float((unsigned)h << 16);
}
__device__ __forceinline__ void gload_lds16(const void* g, void* l) {
    __builtin_amdgcn_global_load_lds(
        (const __attribute__((address_space(1))) void*)g,
        (__attribute__((address_space(3))) void*)l, 16, 0, 0);
}
__device__ __forceinline__ unsigned fkey(float f) {
    unsigned u = __float_as_uint(f);
    return (u & 0x80000000u) ? ~u : (u | 0x80000000u);
}

#define MFMA_BF16 __builtin_amdgcn_mfma_f32_16x16x32_bf16

// =====================================================================
// cbpack: pre-split codebooks to bf16x3 AND reorder into MFMA fragment
// order (group g = ((q*128+cg)*8+k); lane l holds col cg*16+(l&15),
// dims k*32+(l>>4)*8..+8). Wave b-load = one coalesced 1KB read.
// =====================================================================
__global__ __launch_bounds__(256)
void cbpack_kernel(const float* __restrict__ cb, u16* __restrict__ f0,
                   u16* __restrict__ f1, u16* __restrict__ f2)
{
    const int g    = blockIdx.x * 4 + (threadIdx.x >> 6);  // 0..8191
    const int lane = threadIdx.x & 63;
    const int q = g >> 10, rem = g & 1023, cg = rem >> 3, k = rem & 7;
    const int col = cg * 16 + (lane & 15);
    const int d0  = k * 32 + (lane >> 4) * 8;
    const float* src = cb + ((size_t)q * K_ + col) * D_ + d0;
    float4 va = *(const float4*)src, vb = *(const float4*)(src + 4);
    float xs[8] = {va.x, va.y, va.z, va.w, vb.x, vb.y, vb.z, vb.w};
    u16 h[8], m[8], l8[8];
#pragma unroll
    for (int e = 0; e < 8; e++) {
        h[e] = f2bf(xs[e]);
        float r1 = xs[e] - bf2f(h[e]);
        m[e] = f2bf(r1);
        r1 -= bf2f(m[e]);
        l8[e] = f2bf(r1);
    }
    const size_t off = ((size_t)g * 64 + lane) * 8;
    *(ushort4*)(f0 + off)     = make_ushort4(h[0], h[1], h[2], h[3]);
    *(ushort4*)(f0 + off + 4) = make_ushort4(h[4], h[5], h[6], h[7]);
    *(ushort4*)(f1 + off)     = make_ushort4(m[0], m[1], m[2], m[3]);
    *(ushort4*)(f1 + off + 4) = make_ushort4(m[4], m[5], m[6], m[7]);
    *(ushort4*)(f2 + off)     = make_ushort4(l8[0], l8[1], l8[2], l8[3]);
    *(ushort4*)(f2 + off + 4) = make_ushort4(l8[4], l8[5], l8[6], l8[7]);
}

// =====================================================================
// vq_fused v8: R12's proven fused structure (ROWS=32, 256 blocks, 512
// threads, rs+planes in LDS, fragment-packed codebook). Inner loop
// re-nested: n-groups of 2 with acc[2][2] (16 regs vs 64) -> frees 48
// VGPRs to batch 6 b-loads ahead of each 24-MFMA block (2x R12's load
// depth) while staying under the 128-VGPR allocation (no spill).
// Indices bit-identical (packed-u64 min, fold-order independent).
// =====================================================================
#define ROWS 32
__global__ __launch_bounds__(512)
void vq_fused(const float* __restrict__ z,       // B_ x D_ fp32 (never modified)
              const float* __restrict__ CB,      // Q x K x D fp32
              const u16* __restrict__ cbF0, const u16* __restrict__ cbF1,
              const u16* __restrict__ cbF2,      // fragment-packed planes
              const float* __restrict__ cnorm,   // Q x K
              u16* __restrict__ qplane,          // out: B_ x D_ bf16 quant
              float* __restrict__ out_idx,       // B_ x Q
              float* __restrict__ loss_acc)      // Q
{
    __shared__ float rs[ROWS * 256];
    __shared__ u16 pl0[ROWS * 256];
    __shared__ u16 pl1[ROWS * 256];
    __shared__ u16 pl2[ROWS * 256];
    __shared__ u64 wmin[ROWS][8];
    __shared__ u64 winner[ROWS];

    const int tid  = threadIdx.x;
    const int lane = tid & 63;
    const int wv   = tid >> 6;
    const int row0 = blockIdx.x * ROWS;

    // ---- load z -> rs ----
#pragma unroll
    for (int j = 0; j < 4; j++) {
        int g = tid + j * 512;                       // 2048 float4 granules
        ((float4*)rs)[g] = ((const float4*)(z + (size_t)row0 * D_))[g];
    }
    __syncthreads();

    auto splitPlanes = [&]() {
#pragma unroll
        for (int j = 0; j < 2; j++) {
            int c = tid + j * 512;                   // 1024 chunks of 8 elems
            int r = c >> 5, kc = c & 31;
            const float* src = rs + r * 256 + kc * 8;
            int phys = kc ^ (r & 7);
            u16 h[8], m[8], l[8];
#pragma unroll
            for (int e = 0; e < 8; e++) {
                float x = src[e];
                h[e] = f2bf(x);
                float r1 = x - bf2f(h[e]);
                m[e] = f2bf(r1);
                r1 -= bf2f(m[e]);
                l[e] = f2bf(r1);
            }
            int o = r * 256 + phys * 8;
            *(ushort4*)(pl0 + o)     = make_ushort4(h[0], h[1], h[2], h[3]);
            *(ushort4*)(pl0 + o + 4) = make_ushort4(h[4], h[5], h[6], h[7]);
            *(ushort4*)(pl1 + o)     = make_ushort4(m[0], m[1], m[2], m[3]);
            *(ushort4*)(pl1 + o + 4) = make_ushort4(m[4], m[5], m[6], m[7]);
            *(ushort4*)(pl2 + o)     = make_ushort4(l[0], l[1], l[2], l[3]);
            *(ushort4*)(pl2 + o + 4) = make_ushort4(l[4], l[5], l[6], l[7]);
        }
    };
    splitPlanes();
    __syncthreads();

    for (int q = 0; q < Q_; q++) {
        const float* cnq = cnorm + (size_t)q * K_;

        u64 best8[2][4];
#pragma unroll
        for (int mf = 0; mf < 2; mf++)
#pragma unroll
            for (int r = 0; r < 4; r++) best8[mf][r] = ~0ull;

        // ---- distance MFMA: 2 halves x 4 groups of 2 n-frags ----
#pragma unroll
        for (int half = 0; half < 2; half++) {
            const int colh = wv * 256 + half * 128;
            const int cg0h = colh >> 4;              // 16-col group base
#pragma unroll
            for (int gg = 0; gg < 4; gg++) {
                f32x4 acc[2][2];
#pragma unroll
                for (int mf = 0; mf < 2; mf++)
#pragma unroll
                    for (int n = 0; n < 2; n++)
                        acc[mf][n] = (f32x4){0.f, 0.f, 0.f, 0.f};

                for (int k = 0; k < 8; k++) {
                    // A fragments (LDS, swizzled)
                    bf16x8 a0[2], a1[2], a2[2];
#pragma unroll
                    for (int mf = 0; mf < 2; mf++) {
                        int r = (lane & 15) + mf * 16;
                        int phys = (k * 4 + (lane >> 4)) ^ (r & 7);
                        int o = r * 256 + phys * 8;
                        a0[mf] = *(const bf16x8*)(pl0 + o);
                        a1[mf] = *(const bf16x8*)(pl1 + o);
                        a2[mf] = *(const bf16x8*)(pl2 + o);
                    }
                    // batch the group's 6 b-fragment loads
                    bf16x8 b0[2], b1[2], b2[2];
#pragma unroll
                    for (int n = 0; n < 2; n++) {
                        size_t fb = (((size_t)(q << 10)
                                      + (cg0h + gg * 2 + n) * 8 + k) << 9)
                                    + lane * 8;
                        b0[n] = *(const bf16x8*)(cbF0 + fb);
                        b1[n] = *(const bf16x8*)(cbF1 + fb);
                        b2[n] = *(const bf16x8*)(cbF2 + fb);
                    }
#pragma unroll
                    for (int n = 0; n < 2; n++) {
#pragma unroll
                        for (int mf = 0; mf < 2; mf++) {
                            acc[mf][n] = MFMA_BF16(a0[mf], b0[n], acc[mf][n], 0, 0, 0);
                            acc[mf][n] = MFMA_BF16(a1[mf], b0[n], acc[mf][n], 0, 0, 0);
                            acc[mf][n] = MFMA_BF16(a0[mf], b1[n], acc[mf][n], 0, 0, 0);
                            acc[mf][n] = MFMA_BF16(a1[mf], b1[n], acc[mf][n], 0, 0, 0);
                            acc[mf][n] = MFMA_BF16(a2[mf], b0[n], acc[mf][n], 0, 0, 0);
                            acc[mf][n] = MFMA_BF16(a0[mf], b2[n], acc[mf][n], 0, 0, 0);
                        }
                    }
                }
                // fold this group into per-(mf,r) best
#pragma unroll
                for (int n = 0; n < 2; n++) {
                    int col = colh + (gg * 2 + n) * 16 + (lane & 15);
                    float cn = cnq[col];
#pragma unroll
                    for (int mf = 0; mf < 2; mf++)
#pragma unroll
                        for (int r = 0; r < 4; r++) {
                            float d = cn - 2.0f * acc[mf][n][r];
                            u64 p = ((u64)fkey(d) << 32) | (unsigned)col;
                            if (p < best8[mf][r]) best8[mf][r] = p;
                        }
                }
            }
        }

        // ---- cross-lane (16 cols) then cross-wave argmin ----
#pragma unroll
        for (int mf = 0; mf < 2; mf++)
#pragma unroll
            for (int r = 0; r < 4; r++) {
                u64 p = best8[mf][r];
#pragma unroll
                for (int msk = 1; msk <= 8; msk <<= 1) {
                    u64 o = __shfl_xor(p, msk, 64);
                    if (o < p) p = o;
                }
                if ((lane & 15) == 0)
                    wmin[mf * 16 + (lane >> 4) * 4 + r][wv] = p;
            }
        __syncthreads();
        if (tid < ROWS) {
            u64 m = wmin[tid][0];
#pragma unroll
            for (int w2 = 1; w2 < 8; w2++) { u64 o = wmin[tid][w2]; if (o < m) m = o; }
            winner[tid] = m;
            out_idx[(size_t)(row0 + tid) * Q_ + q] = (float)(unsigned)(m & 0xffffffffu);
        }
        __syncthreads();

        // ---- residual update + loss ----
        float lsum = 0.f;
#pragma unroll
        for (int j = 0; j < 4; j++) {
            int g = tid + j * 512;
            int r = g >> 6;
            unsigned idx = (unsigned)(winner[r] & 0xffffffffu);
            const float4 cv = *(const float4*)(CB + ((size_t)q * K_ + idx) * D_ + (g & 63) * 4);
            float4 rv = ((float4*)rs)[g];
            float dx = rv.x - cv.x, dy = rv.y - cv.y,
                  dz = rv.z - cv.z, dw = rv.w - cv.w;
            lsum += dx * dx + dy * dy + dz * dz + dw * dw;
            ((float4*)rs)[g] = make_float4(dx, dy, dz, dw);
        }
#pragma unroll
        for (int o = 32; o > 0; o >>= 1) lsum += __shfl_down(lsum, o, 64);
        if (lane == 0) atomicAdd(&loss_acc[q], lsum);
        __syncthreads();

        if (q < Q_ - 1) { splitPlanes(); __syncthreads(); }
    }

    // ---- quant = z - resid_final -> bf16 plane for decoder ----
#pragma unroll
    for (int j = 0; j < 2; j++) {
        int c = tid + j * 512;
        int e0 = c * 8;
        const float* zp = z + (size_t)row0 * D_ + e0;
        float4 za = *(const float4*)zp, zb = *(const float4*)(zp + 4);
        float4 ra = *(const float4*)(rs + e0), rb = *(const float4*)(rs + e0 + 4);
        *(ushort4*)(qplane + (size_t)row0 * D_ + e0) =
            make_ushort4(f2bf(za.x - ra.x), f2bf(za.y - ra.y),
                         f2bf(za.z - ra.z), f2bf(za.w - ra.w));
        *(ushort4*)(qplane + (size_t)row0 * D_ + e0 + 4) =
            make_ushort4(f2bf(zb.x - rb.x), f2bf(zb.y - rb.y),
                         f2bf(zb.z - rb.z), f2bf(zb.w - rb.w));
    }
}

// =====================================================================
// gemm2: 256x128 tile, 512 threads, 2-phase prefetch, XCD swizzle
// =====================================================================
template<int NSA, int NSB, int RELU, int NSO, int WF32>
__global__ __launch_bounds__(512)
void gemm2(const u16* __restrict__ A0, const u16* __restrict__ A1,
           const u16* __restrict__ A2,
           const u16* __restrict__ B0, const u16* __restrict__ B1,
           const u16* __restrict__ B2,
           const float* __restrict__ bias,
           float* __restrict__ C,
           u16* __restrict__ C0, u16* __restrict__ C1, u16* __restrict__ C2,
           int N, int Kd)
{
    constexpr int HALF = NSA * 16384 + NSB * 8192;
    __shared__ __align__(16) char smem[2 * HALF];
    const int tid  = threadIdx.x;
    const int lane = tid & 63;
    const int wid  = tid >> 6;
    const int wr   = wid >> 1, wc = wid & 1;

    const int nwg  = gridDim.x;
    const int orig = blockIdx.x;
    const int xcd  = orig & 7;
    const int q8 = nwg >> 3, r8 = nwg & 7;
    const int wgid = (xcd < r8 ? xcd * (q8 + 1)
                               : r8 * (q8 + 1) + (xcd - r8) * q8) + (orig >> 3);
    const int gx = N >> 7;
    const int bx = wgid % gx;
    const int by = wgid / gx;
    const int row0 = by * 256;
    const int col0 = bx * 128;

    const u16* asrc[3][2];
    const u16* bsrc[3];
#pragma unroll
    for (int h = 0; h < 2; h++) {
        int ch = h * 512 + tid;
        int r  = ch >> 2;
        int kc = (ch & 3) ^ ((r >> 1) & 3);
        size_t off = (size_t)(row0 + r) * Kd + kc * 8;
        asrc[0][h] = A0 + off;
        if constexpr (NSA >= 3) { asrc[1][h] = A1 + off; asrc[2][h] = A2 + off; }
    }
    {
        int r  = tid >> 2;
        int kc = (tid & 3) ^ ((r >> 1) & 3);
        size_t off = (size_t)(col0 + r) * Kd + kc * 8;
        bsrc[0] = B0 + off;
        if constexpr (NSB >= 3) { bsrc[1] = B1 + off; bsrc[2] = B2 + off; }
    }

    auto stage = [&](int c) {
        char* base = smem + c * HALF;
#pragma unroll
        for (int s = 0; s < NSA; s++)
#pragma unroll
            for (int h = 0; h < 2; h++) {
                gload_lds16(asrc[s][h], base + s * 16384 + (h * 512 + tid) * 16);
                asrc[s][h] += 32;
            }
#pragma unroll
        for (int s = 0; s < NSB; s++) {
            gload_lds16(bsrc[s], base + NSA * 16384 + s * 8192 + tid * 16);
            bsrc[s] += 32;
        }
    };

    f32x4 acc[4][4];
#pragma unroll
    for (int m = 0; m < 4; m++)
#pragma unroll
        for (int n = 0; n < 4; n++) acc[m][n] = (f32x4){0.f, 0.f, 0.f, 0.f};

    const unsigned fro = (unsigned)((lane & 15) * 64
        + (((lane >> 4) ^ (((lane & 15) >> 1) & 3)) * 16));

    const int nt = Kd >> 5;
    int cur = 0;
    stage(0);
    __syncthreads();

    for (int t = 0; t < nt; t++) {
        if (t + 1 < nt) stage(cur ^ 1);
        const char* base = smem + cur * HALF;
        bf16x8 bfr[4][3];
#pragma unroll
        for (int n = 0; n < 4; n++)
#pragma unroll
            for (int s = 0; s < NSB; s++)
                bfr[n][s] = *(const bf16x8*)(base + NSA * 16384 + s * 8192
                                             + (wc * 64 + n * 16) * 64 + fro);
#pragma unroll
        for (int m = 0; m < 4; m++) {
            bf16x8 af[3];
#pragma unroll
            for (int s = 0; s < NSA; s++)
                af[s] = *(const bf16x8*)(base + s * 16384
                                         + (wr * 64 + m * 16) * 64 + fro);
#pragma unroll
            for (int n = 0; n < 4; n++) {
                acc[m][n] = MFMA_BF16(af[0], bfr[n][0], acc[m][n], 0, 0, 0);
                if constexpr (NSA >= 3 && NSB >= 3) {
                    acc[m][n] = MFMA_BF16(af[1], bfr[n][0], acc[m][n], 0, 0, 0);
                    acc[m][n] = MFMA_BF16(af[0], bfr[n][1], acc[m][n], 0, 0, 0);
                    acc[m][n] = MFMA_BF16(af[1], bfr[n][1], acc[m][n], 0, 0, 0);
                    acc[m][n] = MFMA_BF16(af[2], bfr[n][0], acc[m][n], 0, 0, 0);
                    acc[m][n] = MFMA_BF16(af[0], bfr[n][2], acc[m][n], 0, 0, 0);
                }
            }
        }
        __syncthreads();
        cur ^= 1;
    }

    const int rbase = row0 + wr * 64 + (lane >> 4) * 4;
    const int cbase = col0 + wc * 64 + (lane & 15);
    float bv[4];
#pragma unroll
    for (int n = 0; n < 4; n++) bv[n] = bias[cbase + n * 16];
#pragma unroll
    for (int m = 0; m < 4; m++)
#pragma unroll
        for (int n = 0; n < 4; n++)
#pragma unroll
            for (int r = 0; r < 4; r++) {
                float o = acc[m][n][r] + bv[n];
                if constexpr (RELU) o = fmaxf(o, 0.f);
                size_t off = (size_t)(rbase + m * 16 + r) * N + (cbase + n * 16);
                if constexpr (WF32) C[off] = o;
                if constexpr (NSO >= 1) {
                    u16 p0 = f2bf(o);
                    C0[off] = p0;
                    if constexpr (NSO >= 3) {
                        float r1 = o - bf2f(p0);
                        u16 p1 = f2bf(r1);
                        C1[off] = p1;
                        r1 -= bf2f(p1);
                        C2[off] = f2bf(r1);
                    }
                }
            }
}

// =====================================================================
// gemm_mfma: 128x128 / 4-wave kernel (small-N GEMMs: enc G2/G3, dec1)
// =====================================================================
template<int NSA, int NSB, int RELU, int NSO, int WF32>
__global__ __launch_bounds__(256)
void gemm_mfma(const u16* __restrict__ A0, const u16* __restrict__ A1,
               const u16* __restrict__ A2,
               const u16* __restrict__ B0, const u16* __restrict__ B1,
               const u16* __restrict__ B2,
               const float* __restrict__ bias,
               float* __restrict__ C,
               u16* __restrict__ C0, u16* __restrict__ C1, u16* __restrict__ C2,
               int M, int N, int Kd)
{
    constexpr int NP = NSA + NSB;
    __shared__ __align__(16) char smem[NP * 8192];
    const int tid  = threadIdx.x;
    const int lane = tid & 63;
    const int wid  = tid >> 6;
    const int wr   = wid >> 1, wc = wid & 1;
    const int row0 = blockIdx.y * 128;
    const int col0 = blockIdx.x * 128;

    const u16* asrc[3][2];
    const u16* bsrc[3][2];
#pragma unroll
    for (int h = 0; h < 2; h++) {
        int ch = h * 256 + tid;
        int r  = ch >> 2;
        int kc = (ch & 3) ^ ((r >> 1) & 3);
        size_t aoff = (size_t)(row0 + r) * Kd + kc * 8;
        size_t boff = (size_t)(col0 + r) * Kd + kc * 8;
        asrc[0][h] = A0 + aoff;
        if constexpr (NSA >= 3) { asrc[1][h] = A1 + aoff; asrc[2][h] = A2 + aoff; }
        bsrc[0][h] = B0 + boff;
        if constexpr (NSB >= 3) { bsrc[1][h] = B1 + boff; bsrc[2][h] = B2 + boff; }
    }

    f32x4 acc[4][4];
#pragma unroll
    for (int m = 0; m < 4; m++)
#pragma unroll
        for (int n = 0; n < 4; n++) acc[m][n] = (f32x4){0.f, 0.f, 0.f, 0.f};

    const unsigned fro = (unsigned)((lane & 15) * 64
        + (((lane >> 4) ^ (((lane & 15) >> 1) & 3)) * 16));

    for (int k0 = 0; k0 < Kd; k0 += 32) {
#pragma unroll
        for (int s = 0; s < NSA; s++)
#pragma unroll
            for (int h = 0; h < 2; h++) {
                gload_lds16(asrc[s][h], smem + s * 8192 + (h * 256 + tid) * 16);
                asrc[s][h] += 32;
            }
#pragma unroll
        for (int s = 0; s < NSB; s++)
#pragma unroll
            for (int h = 0; h < 2; h++) {
                gload_lds16(bsrc[s][h],
                            smem + (NSA + s) * 8192 + (h * 256 + tid) * 16);
                bsrc[s][h] += 32;
            }
        __syncthreads();

        bf16x8 bfr[4][3];
#pragma unroll
        for (int n = 0; n < 4; n++)
#pragma unroll
            for (int s = 0; s < NSB; s++)
                bfr[n][s] = *(const bf16x8*)(smem + (NSA + s) * 8192
                                             + (wc * 64 + n * 16) * 64 + fro);
#pragma unroll
        for (int m = 0; m < 4; m++) {
            bf16x8 af[3];
#pragma unroll
            for (int s = 0; s < NSA; s++)
                af[s] = *(const bf16x8*)(smem + s * 8192
                                         + (wr * 64 + m * 16) * 64 + fro);
#pragma unroll
            for (int n = 0; n < 4; n++) {
                acc[m][n] = MFMA_BF16(af[0], bfr[n][0], acc[m][n], 0, 0, 0);
                if constexpr (NSA >= 3 && NSB >= 3) {
                    acc[m][n] = MFMA_BF16(af[1], bfr[n][0], acc[m][n], 0, 0, 0);
                    acc[m][n] = MFMA_BF16(af[0], bfr[n][1], acc[m][n], 0, 0, 0);
                    acc[m][n] = MFMA_BF16(af[1], bfr[n][1], acc[m][n], 0, 0, 0);
                    acc[m][n] = MFMA_BF16(af[2], bfr[n][0], acc[m][n], 0, 0, 0);
                    acc[m][n] = MFMA_BF16(af[0], bfr[n][2], acc[m][n], 0, 0, 0);
                }
            }
        }
        __syncthreads();
    }

    const int rbase = row0 + wr * 64 + (lane >> 4) * 4;
    const int cbase = col0 + wc * 64 + (lane & 15);
    float bv[4];
#pragma unroll
    for (int n = 0; n < 4; n++) bv[n] = bias[cbase + n * 16];
#pragma unroll
    for (int m = 0; m < 4; m++)
#pragma unroll
        for (int n = 0; n < 4; n++)
#pragma unroll
            for (int r = 0; r < 4; r++) {
                float o = acc[m][n][r] + bv[n];
                if constexpr (RELU) o = fmaxf(o, 0.f);
                size_t off = (size_t)(rbase + m * 16 + r) * N + (cbase + n * 16);
                if constexpr (WF32) C[off] = o;
                if constexpr (NSO >= 1) {
                    u16 p0 = f2bf(o);
                    C0[off] = p0;
                    if constexpr (NSO >= 3) {
                        float r1 = o - bf2f(p0);
                        u16 p1 = f2bf(r1);
                        C1[off] = p1;
                        r1 -= bf2f(p1);
                        C2[off] = f2bf(r1);
                    }
                }
            }
}

// ---------------- weight transpose + split prepass ----------------
template<int NS>
__global__ __launch_bounds__(256)
void wsplit_kernel(const float* __restrict__ W, u16* __restrict__ T0,
                   u16* __restrict__ T1, u16* __restrict__ T2, int Kd, int N)
{
    __shared__ float t[32][33];
    const int tx = threadIdx.x & 31, ty = threadIdx.x >> 5;
    const int n0 = blockIdx.x * 32, k0 = blockIdx.y * 32;
#pragma unroll
    for (int r = 0; r < 4; r++)
        t[ty + r * 8][tx] = W[(size_t)(k0 + ty + r * 8) * N + n0 + tx];
    __syncthreads();
#pragma unroll
    for (int r = 0; r < 4; r++) {
        int n = n0 + ty + r * 8, k = k0 + tx;
        float v = t[tx][ty + r * 8];
        u16 h = f2bf(v);
        T0[(size_t)n * Kd + k] = h;
        if constexpr (NS >= 2) {
            float rr = v - bf2f(h);
            u16 m = f2bf(rr);
            T1[(size_t)n * Kd + k] = m;
            if constexpr (NS >= 3) { rr -= bf2f(m); T2[(size_t)n * Kd + k] = f2bf(rr); }
        }
    }
}

// ---------------- elementwise 3-plane split (x) ----------------
__global__ __launch_bounds__(256)
void esplit3_kernel(const float* __restrict__ src, u16* __restrict__ s0,
                    u16* __restrict__ s1, u16* __restrict__ s2)
{
    size_t i = (size_t)blockIdx.x * 256 + threadIdx.x;
    float4 v = ((const float4*)src)[i];
    float x[4] = {v.x, v.y, v.z, v.w};
    u16 h[4], m[4], l[4];
#pragma unroll
    for (int e = 0; e < 4; e++) {
        h[e] = f2bf(x[e]);
        float r1 = x[e] - bf2f(h[e]);
        m[e] = f2bf(r1);
        r1 -= bf2f(m[e]);
        l[e] = f2bf(r1);
    }
    ((ushort4*)s0)[i] = make_ushort4(h[0], h[1], h[2], h[3]);
    ((ushort4*)s1)[i] = make_ushort4(m[0], m[1], m[2], m[3]);
    ((ushort4*)s2)[i] = make_ushort4(l[0], l[1], l[2], l[3]);
}

__global__ void cnorm_kernel(const float* __restrict__ cb, float* __restrict__ cn)
{
    const int lane = threadIdx.x & 63;
    const int w = threadIdx.x >> 6;
    const int row = blockIdx.x * 4 + w;
    const float4 v = *(const float4*)(&cb[(size_t)row * D_ + lane * 4]);
    float s = v.x * v.x + v.y * v.y + v.z * v.z + v.w * v.w;
#pragma unroll
    for (int o = 32; o > 0; o >>= 1) s += __shfl_down(s, o, 64);
    if (lane == 0) cn[row] = s;
}

__global__ void loss_write_kernel(const float* __restrict__ loss_acc,
                                  float* __restrict__ out_loss)
{
    int q = threadIdx.x;
    if (q < Q_) out_loss[q] = loss_acc[q] * (1.0f / ((float)B_ * (float)D_));
}

// ---------------- launch ----------------
extern "C" void kernel_launch(void* const* d_in, const int* in_sizes, int n_in,
                              void* d_out, int out_size, void* d_ws, size_t ws_size,
                              hipStream_t stream)
{
    const float* x    = (const float*)d_in[0];
    const float* e_w0 = (const float*)d_in[1];
    const float* e_b0 = (const float*)d_in[2];
    const float* e_w1 = (const float*)d_in[3];
    const float* e_b1 = (const float*)d_in[4];
    const float* e_w2 = (const float*)d_in[5];
    const float* e_b2 = (const float*)d_in[6];
    const float* d_w0 = (const float*)d_in[7];
    const float* d_b0 = (const float*)d_in[8];
    const float* d_w1 = (const float*)d_in[9];
    const float* d_b1 = (const float*)d_in[10];
    const float* d_w2 = (const float*)d_in[11];
    const float* d_b2 = (const float*)d_in[12];
    const float* codebooks = (const float*)d_in[13];

    float* out = (float*)d_out;
    float* out_decoded = out;
    float* out_idx     = out + (size_t)B_ * IN_;
    float* out_loss    = out_idx + (size_t)B_ * Q_;

    char* w = (char*)d_ws;
    auto alloc = [&](size_t bytes) {
        char* r = w; w += (bytes + 255) & ~(size_t)255; return r;
    };
    u16* ew0t = (u16*)alloc((size_t)3 * IN_ * H0_ * 2);
    u16* ew1t = (u16*)alloc((size_t)3 * H0_ * H1_ * 2);
    u16* ew2t = (u16*)alloc((size_t)3 * H1_ * D_ * 2);
    u16* dw0t = (u16*)alloc((size_t)D_ * H1_ * 2);
    u16* dw1t = (u16*)alloc((size_t)H1_ * H0_ * 2);
    u16* dw2t = (u16*)alloc((size_t)H0_ * IN_ * 2);
    u16* cbF  = (u16*)alloc((size_t)3 * Q_ * K_ * D_ * 2);   // fragment-packed
    float* cnorm = (float*)alloc((size_t)Q_ * K_ * 4);
    float* loss  = (float*)alloc(64);
    float* zbuf  = (float*)alloc((size_t)B_ * D_ * 4);
    u16* qplane  = (u16*)alloc((size_t)B_ * D_ * 2);
    char* regX = alloc((size_t)3 * B_ * IN_ * 2);
    u16* xp0 = (u16*)regX;
    u16* xp1 = xp0 + (size_t)B_ * IN_;
    u16* xp2 = xp1 + (size_t)B_ * IN_;
    u16* h1p0 = (u16*)regX;                       // after G1 consumed
    u16* h1p1 = h1p0 + (size_t)B_ * H1_;
    u16* h1p2 = h1p1 + (size_t)B_ * H1_;
    u16* dh1p = h1p2 + (size_t)B_ * H1_;
    u16* dh0p = dh1p + (size_t)B_ * H1_;
    char* regH = alloc((size_t)3 * B_ * H0_ * 2);
    u16* h0p0 = (u16*)regH;
    u16* h0p1 = h0p0 + (size_t)B_ * H0_;
    u16* h0p2 = h0p1 + (size_t)B_ * H0_;

    const size_t ew0s = (size_t)IN_ * H0_, ew1s = (size_t)H0_ * H1_,
                 ew2s = (size_t)H1_ * D_, cbsz = (size_t)Q_ * K_ * D_;

    // ---- init + prepasses ----
    hipMemsetAsync(loss, 0, 64, stream);
    esplit3_kernel<<<(size_t)B_ * IN_ / 1024, 256, 0, stream>>>(x, xp0, xp1, xp2);
    cbpack_kernel<<<2048, 256, 0, stream>>>(
        codebooks, cbF, cbF + cbsz, cbF + 2 * cbsz);
    wsplit_kernel<3><<<dim3(H0_ / 32, IN_ / 32), 256, 0, stream>>>(
        e_w0, ew0t, ew0t + ew0s, ew0t + 2 * ew0s, IN_, H0_);
    wsplit_kernel<3><<<dim3(H1_ / 32, H0_ / 32), 256, 0, stream>>>(
        e_w1, ew1t, ew1t + ew1s, ew1t + 2 * ew1s, H0_, H1_);
    wsplit_kernel<3><<<dim3(D_ / 32, H1_ / 32), 256, 0, stream>>>(
        e_w2, ew2t, ew2t + ew2s, ew2t + 2 * ew2s, H1_, D_);
    wsplit_kernel<1><<<dim3(H1_ / 32, D_ / 32), 256, 0, stream>>>(
        d_w0, dw0t, nullptr, nullptr, D_, H1_);
    wsplit_kernel<1><<<dim3(H0_ / 32, H1_ / 32), 256, 0, stream>>>(
        d_w1, dw1t, nullptr, nullptr, H1_, H0_);
    wsplit_kernel<1><<<dim3(IN_ / 32, H0_ / 32), 256, 0, stream>>>(
        d_w2, dw2t, nullptr, nullptr, H0_, IN_);
    cnorm_kernel<<<(Q_ * K_) / 4, 256, 0, stream>>>(codebooks, cnorm);

    // ---- encoder ----
    gemm2<3, 3, 1, 3, 0><<<(H0_ / 128) * (B_ / 256), 512, 0, stream>>>(
        xp0, xp1, xp2, ew0t, ew0t + ew0s, ew0t + 2 * ew0s, e_b0,
        nullptr, h0p0, h0p1, h0p2, H0_, IN_);
    gemm_mfma<3, 3, 1, 3, 0><<<dim3(H1_ / 128, B_ / 128), 256, 0, stream>>>(
        h0p0, h0p1, h0p2, ew1t, ew1t + ew1s, ew1t + 2 * ew1s, e_b1,
        nullptr, h1p0, h1p1, h1p2, B_, H1_, H0_);
    gemm_mfma<3, 3, 0, 0, 1><<<dim3(D_ / 128, B_ / 128), 256, 0, stream>>>(
        h1p0, h1p1, h1p2, ew2t, ew2t + ew2s, ew2t + 2 * ew2s, e_b2,
        zbuf, nullptr, nullptr, nullptr, B_, D_, H1_);

    // ---- fused residual VQ ----
    vq_fused<<<B_ / ROWS, 512, 0, stream>>>(
        zbuf, codebooks, cbF, cbF + cbsz, cbF + 2 * cbsz, cnorm,
        qplane, out_idx, loss);
    loss_write_kernel<<<1, 64, 0, stream>>>(loss, out_loss);

    // ---- decoder ----
    gemm_mfma<1, 1, 1, 1, 0><<<dim3(H1_ / 128, B_ / 128), 256, 0, stream>>>(
        qplane, nullptr, nullptr, dw0t, nullptr, nullptr, d_b0,
        nullptr, dh1p, nullptr, nullptr, B_, H1_, D_);
    gemm2<1, 1, 1, 1, 0><<<(H0_ / 128) * (B_ / 256), 512, 0, stream>>>(
        dh1p, nullptr, nullptr, dw1t, nullptr, nullptr, d_b1,
        nullptr, dh0p, nullptr, nullptr, H0_, H1_);
    gemm2<1, 1, 0, 0, 1><<<(IN_ / 128) * (B_ / 256), 512, 0, stream>>>(
        dh0p, nullptr, nullptr, dw2t, nullptr, nullptr, d_b2,
        out_decoded, nullptr, nullptr, nullptr, IN_, H0_);
}

// Round 19
// 1022.566 us; speedup vs baseline: 1.4945x; 1.3284x over previous
//
#include <hip/hip_runtime.h>
#include <stdint.h>

#define B_   8192
#define IN_  2048
#define H0_  1024
#define H1_  512
#define D_   256
#define Q_   8
#define K_   2048

typedef unsigned long long u64;
typedef unsigned short u16;
typedef __attribute__((ext_vector_type(8))) short bf16x8;
typedef __attribute__((ext_vector_type(4))) float f32x4;

__device__ __forceinline__ u16 f2bf(float x) {
    unsigned u = __float_as_uint(x);
    return (u16)((u + 0x7fffu + ((u >> 16) & 1u)) >> 16);
}
__device__ __forceinline__ float bf2f(u16 h) {
    return __uint_as_float((unsigned)h << 16);
}
__device__ __forceinline__ void gload_lds16(const void* g, void* l) {
    __builtin_amdgcn_global_load_lds(
        (const __attribute__((address_space(1))) void*)g,
        (__attribute__((address_space(3))) void*)l, 16, 0, 0);
}
__device__ __forceinline__ unsigned fkey(float f) {
    unsigned u = __float_as_uint(f);
    return (u & 0x80000000u) ? ~u : (u | 0x80000000u);
}

#define MFMA_BF16 __builtin_amdgcn_mfma_f32_16x16x32_bf16

// =====================================================================
// cbpack: pre-split codebooks to bf16x3 AND reorder into MFMA fragment
// order. Group g = ((q*128 + cg)*8 + k); within group, lane l holds
// col = cg*16 + (l&15), dims k*32 + (l>>4)*8 .. +8. A wave's b-fragment
// load becomes one fully-coalesced 1KB read.
// =====================================================================
__global__ __launch_bounds__(256)
void cbpack_kernel(const float* __restrict__ cb, u16* __restrict__ f0,
                   u16* __restrict__ f1, u16* __restrict__ f2)
{
    const int g    = blockIdx.x * 4 + (threadIdx.x >> 6);  // 0..8191
    const int lane = threadIdx.x & 63;
    const int q = g >> 10, rem = g & 1023, cg = rem >> 3, k = rem & 7;
    const int col = cg * 16 + (lane & 15);
    const int d0  = k * 32 + (lane >> 4) * 8;
    const float* src = cb + ((size_t)q * K_ + col) * D_ + d0;
    float4 va = *(const float4*)src, vb = *(const float4*)(src + 4);
    float xs[8] = {va.x, va.y, va.z, va.w, vb.x, vb.y, vb.z, vb.w};
    u16 h[8], m[8], l8[8];
#pragma unroll
    for (int e = 0; e < 8; e++) {
        h[e] = f2bf(xs[e]);
        float r1 = xs[e] - bf2f(h[e]);
        m[e] = f2bf(r1);
        r1 -= bf2f(m[e]);
        l8[e] = f2bf(r1);
    }
    const size_t off = ((size_t)g * 64 + lane) * 8;
    *(ushort4*)(f0 + off)     = make_ushort4(h[0], h[1], h[2], h[3]);
    *(ushort4*)(f0 + off + 4) = make_ushort4(h[4], h[5], h[6], h[7]);
    *(ushort4*)(f1 + off)     = make_ushort4(m[0], m[1], m[2], m[3]);
    *(ushort4*)(f1 + off + 4) = make_ushort4(m[4], m[5], m[6], m[7]);
    *(ushort4*)(f2 + off)     = make_ushort4(l8[0], l8[1], l8[2], l8[3]);
    *(ushort4*)(f2 + off + 4) = make_ushort4(l8[4], l8[5], l8[6], l8[7]);
}

// =====================================================================
// vq_fused v4 (R12, proven 715us no-spill): ROWS=32, 256 blocks, rs in
// LDS, acc[2][8] per half, inline just-in-time b-loads (no batching),
// b-loads from the FRAGMENT-PACKED planes (coalesced 1KB/instr).
// =====================================================================
#define ROWS 32
__global__ __launch_bounds__(512)
void vq_fused(const float* __restrict__ z,       // B_ x D_ fp32 (never modified)
              const float* __restrict__ CB,      // Q x K x D fp32
              const u16* __restrict__ cbF0, const u16* __restrict__ cbF1,
              const u16* __restrict__ cbF2,      // fragment-packed planes
              const float* __restrict__ cnorm,   // Q x K
              u16* __restrict__ qplane,          // out: B_ x D_ bf16 quant
              float* __restrict__ out_idx,       // B_ x Q
              float* __restrict__ loss_acc)      // Q
{
    __shared__ float rs[ROWS * 256];
    __shared__ u16 pl0[ROWS * 256];
    __shared__ u16 pl1[ROWS * 256];
    __shared__ u16 pl2[ROWS * 256];
    __shared__ u64 wmin[ROWS][8];
    __shared__ u64 winner[ROWS];

    const int tid  = threadIdx.x;
    const int lane = tid & 63;
    const int wv   = tid >> 6;
    const int row0 = blockIdx.x * ROWS;

    // ---- load z -> rs ----
#pragma unroll
    for (int j = 0; j < 4; j++) {
        int g = tid + j * 512;                       // 2048 float4 granules
        ((float4*)rs)[g] = ((const float4*)(z + (size_t)row0 * D_))[g];
    }
    __syncthreads();

    auto splitPlanes = [&]() {
#pragma unroll
        for (int j = 0; j < 2; j++) {
            int c = tid + j * 512;                   // 1024 chunks of 8 elems
            int r = c >> 5, kc = c & 31;
            const float* src = rs + r * 256 + kc * 8;
            int phys = kc ^ (r & 7);
            u16 h[8], m[8], l[8];
#pragma unroll
            for (int e = 0; e < 8; e++) {
                float x = src[e];
                h[e] = f2bf(x);
                float r1 = x - bf2f(h[e]);
                m[e] = f2bf(r1);
                r1 -= bf2f(m[e]);
                l[e] = f2bf(r1);
            }
            int o = r * 256 + phys * 8;
            *(ushort4*)(pl0 + o)     = make_ushort4(h[0], h[1], h[2], h[3]);
            *(ushort4*)(pl0 + o + 4) = make_ushort4(h[4], h[5], h[6], h[7]);
            *(ushort4*)(pl1 + o)     = make_ushort4(m[0], m[1], m[2], m[3]);
            *(ushort4*)(pl1 + o + 4) = make_ushort4(m[4], m[5], m[6], m[7]);
            *(ushort4*)(pl2 + o)     = make_ushort4(l[0], l[1], l[2], l[3]);
            *(ushort4*)(pl2 + o + 4) = make_ushort4(l[4], l[5], l[6], l[7]);
        }
    };
    splitPlanes();
    __syncthreads();

    for (int q = 0; q < Q_; q++) {
        const float* cnq = cnorm + (size_t)q * K_;

        u64 best8[2][4];
#pragma unroll
        for (int mf = 0; mf < 2; mf++)
#pragma unroll
            for (int r = 0; r < 4; r++) best8[mf][r] = ~0ull;

        // ---- distance MFMA: two 128-col halves per wave ----
#pragma unroll
        for (int half = 0; half < 2; half++) {
            const int colh = wv * 256 + half * 128;
            const int cg0  = colh >> 4;              // 16-col group base
            f32x4 acc[2][8];
#pragma unroll
            for (int mf = 0; mf < 2; mf++)
#pragma unroll
                for (int n = 0; n < 8; n++) acc[mf][n] = (f32x4){0.f, 0.f, 0.f, 0.f};

            for (int k = 0; k < 8; k++) {
                // A fragments (LDS, swizzled)
                bf16x8 a0[2], a1[2], a2[2];
#pragma unroll
                for (int mf = 0; mf < 2; mf++) {
                    int r = (lane & 15) + mf * 16;
                    int phys = (k * 4 + (lane >> 4)) ^ (r & 7);
                    int o = r * 256 + phys * 8;
                    a0[mf] = *(const bf16x8*)(pl0 + o);
                    a1[mf] = *(const bf16x8*)(pl1 + o);
                    a2[mf] = *(const bf16x8*)(pl2 + o);
                }
#pragma unroll
                for (int n = 0; n < 8; n++) {
                    // fragment-packed: group = q*1024 + (cg0+n)*8 + k
                    size_t fb = (((size_t)(q << 10) + (cg0 + n) * 8 + k) << 9)
                                + lane * 8;
                    bf16x8 b0 = *(const bf16x8*)(cbF0 + fb);
                    bf16x8 b1 = *(const bf16x8*)(cbF1 + fb);
                    bf16x8 b2 = *(const bf16x8*)(cbF2 + fb);
#pragma unroll
                    for (int mf = 0; mf < 2; mf++) {
                        acc[mf][n] = MFMA_BF16(a0[mf], b0, acc[mf][n], 0, 0, 0);
                        acc[mf][n] = MFMA_BF16(a1[mf], b0, acc[mf][n], 0, 0, 0);
                        acc[mf][n] = MFMA_BF16(a0[mf], b1, acc[mf][n], 0, 0, 0);
                        acc[mf][n] = MFMA_BF16(a1[mf], b1, acc[mf][n], 0, 0, 0);
                        acc[mf][n] = MFMA_BF16(a2[mf], b0, acc[mf][n], 0, 0, 0);
                        acc[mf][n] = MFMA_BF16(a0[mf], b2, acc[mf][n], 0, 0, 0);
                    }
                }
            }
            // fold this half into per-(mf,r) best
#pragma unroll
            for (int n = 0; n < 8; n++) {
                int col = colh + n * 16 + (lane & 15);
                float cn = cnq[col];
#pragma unroll
                for (int mf = 0; mf < 2; mf++)
#pragma unroll
                    for (int r = 0; r < 4; r++) {
                        float d = cn - 2.0f * acc[mf][n][r];
                        u64 p = ((u64)fkey(d) << 32) | (unsigned)col;
                        if (p < best8[mf][r]) best8[mf][r] = p;
                    }
            }
        }

        // ---- cross-lane (16 cols) then cross-wave argmin ----
#pragma unroll
        for (int mf = 0; mf < 2; mf++)
#pragma unroll
            for (int r = 0; r < 4; r++) {
                u64 p = best8[mf][r];
#pragma unroll
                for (int msk = 1; msk <= 8; msk <<= 1) {
                    u64 o = __shfl_xor(p, msk, 64);
                    if (o < p) p = o;
                }
                if ((lane & 15) == 0)
                    wmin[mf * 16 + (lane >> 4) * 4 + r][wv] = p;
            }
        __syncthreads();
        if (tid < ROWS) {
            u64 m = wmin[tid][0];
#pragma unroll
            for (int w2 = 1; w2 < 8; w2++) { u64 o = wmin[tid][w2]; if (o < m) m = o; }
            winner[tid] = m;
            out_idx[(size_t)(row0 + tid) * Q_ + q] = (float)(unsigned)(m & 0xffffffffu);
        }
        __syncthreads();

        // ---- residual update + loss ----
        float lsum = 0.f;
#pragma unroll
        for (int j = 0; j < 4; j++) {
            int g = tid + j * 512;
            int r = g >> 6;
            unsigned idx = (unsigned)(winner[r] & 0xffffffffu);
            const float4 cv = *(const float4*)(CB + ((size_t)q * K_ + idx) * D_ + (g & 63) * 4);
            float4 rv = ((float4*)rs)[g];
            float dx = rv.x - cv.x, dy = rv.y - cv.y,
                  dz = rv.z - cv.z, dw = rv.w - cv.w;
            lsum += dx * dx + dy * dy + dz * dz + dw * dw;
            ((float4*)rs)[g] = make_float4(dx, dy, dz, dw);
        }
#pragma unroll
        for (int o = 32; o > 0; o >>= 1) lsum += __shfl_down(lsum, o, 64);
        if (lane == 0) atomicAdd(&loss_acc[q], lsum);
        __syncthreads();

        if (q < Q_ - 1) { splitPlanes(); __syncthreads(); }
    }

    // ---- quant = z - resid_final -> bf16 plane for decoder ----
#pragma unroll
    for (int j = 0; j < 2; j++) {
        int c = tid + j * 512;
        int e0 = c * 8;
        const float* zp = z + (size_t)row0 * D_ + e0;
        float4 za = *(const float4*)zp, zb = *(const float4*)(zp + 4);
        float4 ra = *(const float4*)(rs + e0), rb = *(const float4*)(rs + e0 + 4);
        *(ushort4*)(qplane + (size_t)row0 * D_ + e0) =
            make_ushort4(f2bf(za.x - ra.x), f2bf(za.y - ra.y),
                         f2bf(za.z - ra.z), f2bf(za.w - ra.w));
        *(ushort4*)(qplane + (size_t)row0 * D_ + e0 + 4) =
            make_ushort4(f2bf(zb.x - rb.x), f2bf(zb.y - rb.y),
                         f2bf(zb.z - rb.z), f2bf(zb.w - rb.w));
    }
}

// =====================================================================
// gemm2: 256x128 tile, 512 threads, 2-phase prefetch, XCD swizzle
// =====================================================================
template<int NSA, int NSB, int RELU, int NSO, int WF32>
__global__ __launch_bounds__(512)
void gemm2(const u16* __restrict__ A0, const u16* __restrict__ A1,
           const u16* __restrict__ A2,
           const u16* __restrict__ B0, const u16* __restrict__ B1,
           const u16* __restrict__ B2,
           const float* __restrict__ bias,
           float* __restrict__ C,
           u16* __restrict__ C0, u16* __restrict__ C1, u16* __restrict__ C2,
           int N, int Kd)
{
    constexpr int HALF = NSA * 16384 + NSB * 8192;
    __shared__ __align__(16) char smem[2 * HALF];
    const int tid  = threadIdx.x;
    const int lane = tid & 63;
    const int wid  = tid >> 6;
    const int wr   = wid >> 1, wc = wid & 1;

    const int nwg  = gridDim.x;
    const int orig = blockIdx.x;
    const int xcd  = orig & 7;
    const int q8 = nwg >> 3, r8 = nwg & 7;
    const int wgid = (xcd < r8 ? xcd * (q8 + 1)
                               : r8 * (q8 + 1) + (xcd - r8) * q8) + (orig >> 3);
    const int gx = N >> 7;
    const int bx = wgid % gx;
    const int by = wgid / gx;
    const int row0 = by * 256;
    const int col0 = bx * 128;

    const u16* asrc[3][2];
    const u16* bsrc[3];
#pragma unroll
    for (int h = 0; h < 2; h++) {
        int ch = h * 512 + tid;
        int r  = ch >> 2;
        int kc = (ch & 3) ^ ((r >> 1) & 3);
        size_t off = (size_t)(row0 + r) * Kd + kc * 8;
        asrc[0][h] = A0 + off;
        if constexpr (NSA >= 3) { asrc[1][h] = A1 + off; asrc[2][h] = A2 + off; }
    }
    {
        int r  = tid >> 2;
        int kc = (tid & 3) ^ ((r >> 1) & 3);
        size_t off = (size_t)(col0 + r) * Kd + kc * 8;
        bsrc[0] = B0 + off;
        if constexpr (NSB >= 3) { bsrc[1] = B1 + off; bsrc[2] = B2 + off; }
    }

    auto stage = [&](int c) {
        char* base = smem + c * HALF;
#pragma unroll
        for (int s = 0; s < NSA; s++)
#pragma unroll
            for (int h = 0; h < 2; h++) {
                gload_lds16(asrc[s][h], base + s * 16384 + (h * 512 + tid) * 16);
                asrc[s][h] += 32;
            }
#pragma unroll
        for (int s = 0; s < NSB; s++) {
            gload_lds16(bsrc[s], base + NSA * 16384 + s * 8192 + tid * 16);
            bsrc[s] += 32;
        }
    };

    f32x4 acc[4][4];
#pragma unroll
    for (int m = 0; m < 4; m++)
#pragma unroll
        for (int n = 0; n < 4; n++) acc[m][n] = (f32x4){0.f, 0.f, 0.f, 0.f};

    const unsigned fro = (unsigned)((lane & 15) * 64
        + (((lane >> 4) ^ (((lane & 15) >> 1) & 3)) * 16));

    const int nt = Kd >> 5;
    int cur = 0;
    stage(0);
    __syncthreads();

    for (int t = 0; t < nt; t++) {
        if (t + 1 < nt) stage(cur ^ 1);
        const char* base = smem + cur * HALF;
        bf16x8 bfr[4][3];
#pragma unroll
        for (int n = 0; n < 4; n++)
#pragma unroll
            for (int s = 0; s < NSB; s++)
                bfr[n][s] = *(const bf16x8*)(base + NSA * 16384 + s * 8192
                                             + (wc * 64 + n * 16) * 64 + fro);
#pragma unroll
        for (int m = 0; m < 4; m++) {
            bf16x8 af[3];
#pragma unroll
            for (int s = 0; s < NSA; s++)
                af[s] = *(const bf16x8*)(base + s * 16384
                                         + (wr * 64 + m * 16) * 64 + fro);
#pragma unroll
            for (int n = 0; n < 4; n++) {
                acc[m][n] = MFMA_BF16(af[0], bfr[n][0], acc[m][n], 0, 0, 0);
                if constexpr (NSA >= 3 && NSB >= 3) {
                    acc[m][n] = MFMA_BF16(af[1], bfr[n][0], acc[m][n], 0, 0, 0);
                    acc[m][n] = MFMA_BF16(af[0], bfr[n][1], acc[m][n], 0, 0, 0);
                    acc[m][n] = MFMA_BF16(af[1], bfr[n][1], acc[m][n], 0, 0, 0);
                    acc[m][n] = MFMA_BF16(af[2], bfr[n][0], acc[m][n], 0, 0, 0);
                    acc[m][n] = MFMA_BF16(af[0], bfr[n][2], acc[m][n], 0, 0, 0);
                }
            }
        }
        __syncthreads();
        cur ^= 1;
    }

    const int rbase = row0 + wr * 64 + (lane >> 4) * 4;
    const int cbase = col0 + wc * 64 + (lane & 15);
    float bv[4];
#pragma unroll
    for (int n = 0; n < 4; n++) bv[n] = bias[cbase + n * 16];
#pragma unroll
    for (int m = 0; m < 4; m++)
#pragma unroll
        for (int n = 0; n < 4; n++)
#pragma unroll
            for (int r = 0; r < 4; r++) {
                float o = acc[m][n][r] + bv[n];
                if constexpr (RELU) o = fmaxf(o, 0.f);
                size_t off = (size_t)(rbase + m * 16 + r) * N + (cbase + n * 16);
                if constexpr (WF32) C[off] = o;
                if constexpr (NSO >= 1) {
                    u16 p0 = f2bf(o);
                    C0[off] = p0;
                    if constexpr (NSO >= 3) {
                        float r1 = o - bf2f(p0);
                        u16 p1 = f2bf(r1);
                        C1[off] = p1;
                        r1 -= bf2f(p1);
                        C2[off] = f2bf(r1);
                    }
                }
            }
}

// =====================================================================
// gemm_mfma: 128x128 / 4-wave kernel (small-N GEMMs: enc G2/G3, dec1)
// =====================================================================
template<int NSA, int NSB, int RELU, int NSO, int WF32>
__global__ __launch_bounds__(256)
void gemm_mfma(const u16* __restrict__ A0, const u16* __restrict__ A1,
               const u16* __restrict__ A2,
               const u16* __restrict__ B0, const u16* __restrict__ B1,
               const u16* __restrict__ B2,
               const float* __restrict__ bias,
               float* __restrict__ C,
               u16* __restrict__ C0, u16* __restrict__ C1, u16* __restrict__ C2,
               int M, int N, int Kd)
{
    constexpr int NP = NSA + NSB;
    __shared__ __align__(16) char smem[NP * 8192];
    const int tid  = threadIdx.x;
    const int lane = tid & 63;
    const int wid  = tid >> 6;
    const int wr   = wid >> 1, wc = wid & 1;
    const int row0 = blockIdx.y * 128;
    const int col0 = blockIdx.x * 128;

    const u16* asrc[3][2];
    const u16* bsrc[3][2];
#pragma unroll
    for (int h = 0; h < 2; h++) {
        int ch = h * 256 + tid;
        int r  = ch >> 2;
        int kc = (ch & 3) ^ ((r >> 1) & 3);
        size_t aoff = (size_t)(row0 + r) * Kd + kc * 8;
        size_t boff = (size_t)(col0 + r) * Kd + kc * 8;
        asrc[0][h] = A0 + aoff;
        if constexpr (NSA >= 3) { asrc[1][h] = A1 + aoff; asrc[2][h] = A2 + aoff; }
        bsrc[0][h] = B0 + boff;
        if constexpr (NSB >= 3) { bsrc[1][h] = B1 + boff; bsrc[2][h] = B2 + boff; }
    }

    f32x4 acc[4][4];
#pragma unroll
    for (int m = 0; m < 4; m++)
#pragma unroll
        for (int n = 0; n < 4; n++) acc[m][n] = (f32x4){0.f, 0.f, 0.f, 0.f};

    const unsigned fro = (unsigned)((lane & 15) * 64
        + (((lane >> 4) ^ (((lane & 15) >> 1) & 3)) * 16));

    for (int k0 = 0; k0 < Kd; k0 += 32) {
#pragma unroll
        for (int s = 0; s < NSA; s++)
#pragma unroll
            for (int h = 0; h < 2; h++) {
                gload_lds16(asrc[s][h], smem + s * 8192 + (h * 256 + tid) * 16);
                asrc[s][h] += 32;
            }
#pragma unroll
        for (int s = 0; s < NSB; s++)
#pragma unroll
            for (int h = 0; h < 2; h++) {
                gload_lds16(bsrc[s][h],
                            smem + (NSA + s) * 8192 + (h * 256 + tid) * 16);
                bsrc[s][h] += 32;
            }
        __syncthreads();

        bf16x8 bfr[4][3];
#pragma unroll
        for (int n = 0; n < 4; n++)
#pragma unroll
            for (int s = 0; s < NSB; s++)
                bfr[n][s] = *(const bf16x8*)(smem + (NSA + s) * 8192
                                             + (wc * 64 + n * 16) * 64 + fro);
#pragma unroll
        for (int m = 0; m < 4; m++) {
            bf16x8 af[3];
#pragma unroll
            for (int s = 0; s < NSA; s++)
                af[s] = *(const bf16x8*)(smem + s * 8192
                                         + (wr * 64 + m * 16) * 64 + fro);
#pragma unroll
            for (int n = 0; n < 4; n++) {
                acc[m][n] = MFMA_BF16(af[0], bfr[n][0], acc[m][n], 0, 0, 0);
                if constexpr (NSA >= 3 && NSB >= 3) {
                    acc[m][n] = MFMA_BF16(af[1], bfr[n][0], acc[m][n], 0, 0, 0);
                    acc[m][n] = MFMA_BF16(af[0], bfr[n][1], acc[m][n], 0, 0, 0);
                    acc[m][n] = MFMA_BF16(af[1], bfr[n][1], acc[m][n], 0, 0, 0);
                    acc[m][n] = MFMA_BF16(af[2], bfr[n][0], acc[m][n], 0, 0, 0);
                    acc[m][n] = MFMA_BF16(af[0], bfr[n][2], acc[m][n], 0, 0, 0);
                }
            }
        }
        __syncthreads();
    }

    const int rbase = row0 + wr * 64 + (lane >> 4) * 4;
    const int cbase = col0 + wc * 64 + (lane & 15);
    float bv[4];
#pragma unroll
    for (int n = 0; n < 4; n++) bv[n] = bias[cbase + n * 16];
#pragma unroll
    for (int m = 0; m < 4; m++)
#pragma unroll
        for (int n = 0; n < 4; n++)
#pragma unroll
            for (int r = 0; r < 4; r++) {
                float o = acc[m][n][r] + bv[n];
                if constexpr (RELU) o = fmaxf(o, 0.f);
                size_t off = (size_t)(rbase + m * 16 + r) * N + (cbase + n * 16);
                if constexpr (WF32) C[off] = o;
                if constexpr (NSO >= 1) {
                    u16 p0 = f2bf(o);
                    C0[off] = p0;
                    if constexpr (NSO >= 3) {
                        float r1 = o - bf2f(p0);
                        u16 p1 = f2bf(r1);
                        C1[off] = p1;
                        r1 -= bf2f(p1);
                        C2[off] = f2bf(r1);
                    }
                }
            }
}

// ---------------- weight transpose + split prepass ----------------
template<int NS>
__global__ __launch_bounds__(256)
void wsplit_kernel(const float* __restrict__ W, u16* __restrict__ T0,
                   u16* __restrict__ T1, u16* __restrict__ T2, int Kd, int N)
{
    __shared__ float t[32][33];
    const int tx = threadIdx.x & 31, ty = threadIdx.x >> 5;
    const int n0 = blockIdx.x * 32, k0 = blockIdx.y * 32;
#pragma unroll
    for (int r = 0; r < 4; r++)
        t[ty + r * 8][tx] = W[(size_t)(k0 + ty + r * 8) * N + n0 + tx];
    __syncthreads();
#pragma unroll
    for (int r = 0; r < 4; r++) {
        int n = n0 + ty + r * 8, k = k0 + tx;
        float v = t[tx][ty + r * 8];
        u16 h = f2bf(v);
        T0[(size_t)n * Kd + k] = h;
        if constexpr (NS >= 2) {
            float rr = v - bf2f(h);
            u16 m = f2bf(rr);
            T1[(size_t)n * Kd + k] = m;
            if constexpr (NS >= 3) { rr -= bf2f(m); T2[(size_t)n * Kd + k] = f2bf(rr); }
        }
    }
}

// ---------------- elementwise 3-plane split (x) ----------------
__global__ __launch_bounds__(256)
void esplit3_kernel(const float* __restrict__ src, u16* __restrict__ s0,
                    u16* __restrict__ s1, u16* __restrict__ s2)
{
    size_t i = (size_t)blockIdx.x * 256 + threadIdx.x;
    float4 v = ((const float4*)src)[i];
    float x[4] = {v.x, v.y, v.z, v.w};
    u16 h[4], m[4], l[4];
#pragma unroll
    for (int e = 0; e < 4; e++) {
        h[e] = f2bf(x[e]);
        float r1 = x[e] - bf2f(h[e]);
        m[e] = f2bf(r1);
        r1 -= bf2f(m[e]);
        l[e] = f2bf(r1);
    }
    ((ushort4*)s0)[i] = make_ushort4(h[0], h[1], h[2], h[3]);
    ((ushort4*)s1)[i] = make_ushort4(m[0], m[1], m[2], m[3]);
    ((ushort4*)s2)[i] = make_ushort4(l[0], l[1], l[2], l[3]);
}

__global__ void cnorm_kernel(const float* __restrict__ cb, float* __restrict__ cn)
{
    const int lane = threadIdx.x & 63;
    const int w = threadIdx.x >> 6;
    const int row = blockIdx.x * 4 + w;
    const float4 v = *(const float4*)(&cb[(size_t)row * D_ + lane * 4]);
    float s = v.x * v.x + v.y * v.y + v.z * v.z + v.w * v.w;
#pragma unroll
    for (int o = 32; o > 0; o >>= 1) s += __shfl_down(s, o, 64);
    if (lane == 0) cn[row] = s;
}

__global__ void loss_write_kernel(const float* __restrict__ loss_acc,
                                  float* __restrict__ out_loss)
{
    int q = threadIdx.x;
    if (q < Q_) out_loss[q] = loss_acc[q] * (1.0f / ((float)B_ * (float)D_));
}

// ---------------- launch ----------------
extern "C" void kernel_launch(void* const* d_in, const int* in_sizes, int n_in,
                              void* d_out, int out_size, void* d_ws, size_t ws_size,
                              hipStream_t stream)
{
    const float* x    = (const float*)d_in[0];
    const float* e_w0 = (const float*)d_in[1];
    const float* e_b0 = (const float*)d_in[2];
    const float* e_w1 = (const float*)d_in[3];
    const float* e_b1 = (const float*)d_in[4];
    const float* e_w2 = (const float*)d_in[5];
    const float* e_b2 = (const float*)d_in[6];
    const float* d_w0 = (const float*)d_in[7];
    const float* d_b0 = (const float*)d_in[8];
    const float* d_w1 = (const float*)d_in[9];
    const float* d_b1 = (const float*)d_in[10];
    const float* d_w2 = (const float*)d_in[11];
    const float* d_b2 = (const float*)d_in[12];
    const float* codebooks = (const float*)d_in[13];

    float* out = (float*)d_out;
    float* out_decoded = out;
    float* out_idx     = out + (size_t)B_ * IN_;
    float* out_loss    = out_idx + (size_t)B_ * Q_;

    char* w = (char*)d_ws;
    auto alloc = [&](size_t bytes) {
        char* r = w; w += (bytes + 255) & ~(size_t)255; return r;
    };
    u16* ew0t = (u16*)alloc((size_t)3 * IN_ * H0_ * 2);
    u16* ew1t = (u16*)alloc((size_t)3 * H0_ * H1_ * 2);
    u16* ew2t = (u16*)alloc((size_t)3 * H1_ * D_ * 2);
    u16* dw0t = (u16*)alloc((size_t)D_ * H1_ * 2);
    u16* dw1t = (u16*)alloc((size_t)H1_ * H0_ * 2);
    u16* dw2t = (u16*)alloc((size_t)H0_ * IN_ * 2);
    u16* cbF  = (u16*)alloc((size_t)3 * Q_ * K_ * D_ * 2);   // fragment-packed
    float* cnorm = (float*)alloc((size_t)Q_ * K_ * 4);
    float* loss  = (float*)alloc(64);
    float* zbuf  = (float*)alloc((size_t)B_ * D_ * 4);
    u16* qplane  = (u16*)alloc((size_t)B_ * D_ * 2);
    char* regX = alloc((size_t)3 * B_ * IN_ * 2);
    u16* xp0 = (u16*)regX;
    u16* xp1 = xp0 + (size_t)B_ * IN_;
    u16* xp2 = xp1 + (size_t)B_ * IN_;
    u16* h1p0 = (u16*)regX;                       // after G1 consumed
    u16* h1p1 = h1p0 + (size_t)B_ * H1_;
    u16* h1p2 = h1p1 + (size_t)B_ * H1_;
    u16* dh1p = h1p2 + (size_t)B_ * H1_;
    u16* dh0p = dh1p + (size_t)B_ * H1_;
    char* regH = alloc((size_t)3 * B_ * H0_ * 2);
    u16* h0p0 = (u16*)regH;
    u16* h0p1 = h0p0 + (size_t)B_ * H0_;
    u16* h0p2 = h0p1 + (size_t)B_ * H0_;

    const size_t ew0s = (size_t)IN_ * H0_, ew1s = (size_t)H0_ * H1_,
                 ew2s = (size_t)H1_ * D_, cbsz = (size_t)Q_ * K_ * D_;

    // ---- init + prepasses ----
    hipMemsetAsync(loss, 0, 64, stream);
    esplit3_kernel<<<(size_t)B_ * IN_ / 1024, 256, 0, stream>>>(x, xp0, xp1, xp2);
    cbpack_kernel<<<2048, 256, 0, stream>>>(
        codebooks, cbF, cbF + cbsz, cbF + 2 * cbsz);
    wsplit_kernel<3><<<dim3(H0_ / 32, IN_ / 32), 256, 0, stream>>>(
        e_w0, ew0t, ew0t + ew0s, ew0t + 2 * ew0s, IN_, H0_);
    wsplit_kernel<3><<<dim3(H1_ / 32, H0_ / 32), 256, 0, stream>>>(
        e_w1, ew1t, ew1t + ew1s, ew1t + 2 * ew1s, H0_, H1_);
    wsplit_kernel<3><<<dim3(D_ / 32, H1_ / 32), 256, 0, stream>>>(
        e_w2, ew2t, ew2t + ew2s, ew2t + 2 * ew2s, H1_, D_);
    wsplit_kernel<1><<<dim3(H1_ / 32, D_ / 32), 256, 0, stream>>>(
        d_w0, dw0t, nullptr, nullptr, D_, H1_);
    wsplit_kernel<1><<<dim3(H0_ / 32, H1_ / 32), 256, 0, stream>>>(
        d_w1, dw1t, nullptr, nullptr, H1_, H0_);
    wsplit_kernel<1><<<dim3(IN_ / 32, H0_ / 32), 256, 0, stream>>>(
        d_w2, dw2t, nullptr, nullptr, H0_, IN_);
    cnorm_kernel<<<(Q_ * K_) / 4, 256, 0, stream>>>(codebooks, cnorm);

    // ---- encoder ----
    gemm2<3, 3, 1, 3, 0><<<(H0_ / 128) * (B_ / 256), 512, 0, stream>>>(
        xp0, xp1, xp2, ew0t, ew0t + ew0s, ew0t + 2 * ew0s, e_b0,
        nullptr, h0p0, h0p1, h0p2, H0_, IN_);
    gemm_mfma<3, 3, 1, 3, 0><<<dim3(H1_ / 128, B_ / 128), 256, 0, stream>>>(
        h0p0, h0p1, h0p2, ew1t, ew1t + ew1s, ew1t + 2 * ew1s, e_b1,
        nullptr, h1p0, h1p1, h1p2, B_, H1_, H0_);
    gemm_mfma<3, 3, 0, 0, 1><<<dim3(D_ / 128, B_ / 128), 256, 0, stream>>>(
        h1p0, h1p1, h1p2, ew2t, ew2t + ew2s, ew2t + 2 * ew2s, e_b2,
        zbuf, nullptr, nullptr, nullptr, B_, D_, H1_);

    // ---- fused residual VQ ----
    vq_fused<<<B_ / ROWS, 512, 0, stream>>>(
        zbuf, codebooks, cbF, cbF + cbsz, cbF + 2 * cbsz, cnorm,
        qplane, out_idx, loss);
    loss_write_kernel<<<1, 64, 0, stream>>>(loss, out_loss);

    // ---- decoder ----
    gemm_mfma<1, 1, 1, 1, 0><<<dim3(H1_ / 128, B_ / 128), 256, 0, stream>>>(
        qplane, nullptr, nullptr, dw0t, nullptr, nullptr, d_b0,
        nullptr, dh1p, nullptr, nullptr, B_, H1_, D_);
    gemm2<1, 1, 1, 1, 0><<<(H0_ / 128) * (B_ / 256), 512, 0, stream>>>(
        dh1p, nullptr, nullptr, dw1t, nullptr, nullptr, d_b1,
        nullptr, dh0p, nullptr, nullptr, H0_, H1_);
    gemm2<1, 1, 0, 0, 1><<<(IN_ / 128) * (B_ / 256), 512, 0, stream>>>(
        dh0p, nullptr, nullptr, dw2t, nullptr, nullptr, d_b2,
        out_decoded, nullptr, nullptr, nullptr, IN_, H0_);
}

// Round 20
// 875.883 us; speedup vs baseline: 1.7448x; 1.1675x over previous
//
#include <hip/hip_runtime.h>
#include <stdint.h>

#define B_   8192
#define IN_  2048
#define H0_  1024
#define H1_  512
#define D_   256
#define Q_   8
#define K_   2048

typedef unsigned long long u64;
typedef unsigned short u16;
typedef __attribute__((ext_vector_type(8))) short bf16x8;
typedef __attribute__((ext_vector_type(4))) float f32x4;

__device__ __forceinline__ u16 f2bf(float x) {
    unsigned u = __float_as_uint(x);
    return (u16)((u + 0x7fffu + ((u >> 16) & 1u)) >> 16);
}
__device__ __forceinline__ float bf2f(u16 h) {
    return __uint_as_float((unsigned)h << 16);
}
__device__ __forceinline__ void gload_lds16(const void* g, void* l) {
    __builtin_amdgcn_global_load_lds(
        (const __attribute__((address_space(1))) void*)g,
        (__attribute__((address_space(3))) void*)l, 16, 0, 0);
}
__device__ __forceinline__ unsigned fkey(float f) {
    unsigned u = __float_as_uint(f);
    return (u & 0x80000000u) ? ~u : (u | 0x80000000u);
}

#define MFMA_BF16 __builtin_amdgcn_mfma_f32_16x16x32_bf16

// =====================================================================
// cbpack: pre-split codebooks to bf16x3 AND reorder into MFMA fragment
// order. Group g = ((q*128 + cg)*8 + k); within group, lane l holds
// col = cg*16 + (l&15), dims k*32 + (l>>4)*8 .. +8. A wave's b-fragment
// load becomes one fully-coalesced 1KB read.
// =====================================================================
__global__ __launch_bounds__(256)
void cbpack_kernel(const float* __restrict__ cb, u16* __restrict__ f0,
                   u16* __restrict__ f1, u16* __restrict__ f2)
{
    const int g    = blockIdx.x * 4 + (threadIdx.x >> 6);  // 0..8191
    const int lane = threadIdx.x & 63;
    const int q = g >> 10, rem = g & 1023, cg = rem >> 3, k = rem & 7;
    const int col = cg * 16 + (lane & 15);
    const int d0  = k * 32 + (lane >> 4) * 8;
    const float* src = cb + ((size_t)q * K_ + col) * D_ + d0;
    float4 va = *(const float4*)src, vb = *(const float4*)(src + 4);
    float xs[8] = {va.x, va.y, va.z, va.w, vb.x, vb.y, vb.z, vb.w};
    u16 h[8], m[8], l8[8];
#pragma unroll
    for (int e = 0; e < 8; e++) {
        h[e] = f2bf(xs[e]);
        float r1 = xs[e] - bf2f(h[e]);
        m[e] = f2bf(r1);
        r1 -= bf2f(m[e]);
        l8[e] = f2bf(r1);
    }
    const size_t off = ((size_t)g * 64 + lane) * 8;
    *(ushort4*)(f0 + off)     = make_ushort4(h[0], h[1], h[2], h[3]);
    *(ushort4*)(f0 + off + 4) = make_ushort4(h[4], h[5], h[6], h[7]);
    *(ushort4*)(f1 + off)     = make_ushort4(m[0], m[1], m[2], m[3]);
    *(ushort4*)(f1 + off + 4) = make_ushort4(m[4], m[5], m[6], m[7]);
    *(ushort4*)(f2 + off)     = make_ushort4(l8[0], l8[1], l8[2], l8[3]);
    *(ushort4*)(f2 + off + 4) = make_ushort4(l8[4], l8[5], l8[6], l8[7]);
}

// =====================================================================
// vq_fused (R12/R19 proven structure + T5 setprio around MFMA cluster):
// ROWS=32, 256 blocks, rs in LDS, acc[2][8] per half, just-in-time
// b-loads from fragment-packed planes. Waves are independent inside the
// k-loop -> role diversity -> setprio(1) lets MFMA-ready waves win
// arbitration over load-issuing waves (T5, attn-regime).
// =====================================================================
#define ROWS 32
__global__ __launch_bounds__(512)
void vq_fused(const float* __restrict__ z,       // B_ x D_ fp32 (never modified)
              const float* __restrict__ CB,      // Q x K x D fp32
              const u16* __restrict__ cbF0, const u16* __restrict__ cbF1,
              const u16* __restrict__ cbF2,      // fragment-packed planes
              const float* __restrict__ cnorm,   // Q x K
              u16* __restrict__ qplane,          // out: B_ x D_ bf16 quant
              float* __restrict__ out_idx,       // B_ x Q
              float* __restrict__ loss_acc)      // Q
{
    __shared__ float rs[ROWS * 256];
    __shared__ u16 pl0[ROWS * 256];
    __shared__ u16 pl1[ROWS * 256];
    __shared__ u16 pl2[ROWS * 256];
    __shared__ u64 wmin[ROWS][8];
    __shared__ u64 winner[ROWS];

    const int tid  = threadIdx.x;
    const int lane = tid & 63;
    const int wv   = tid >> 6;
    const int row0 = blockIdx.x * ROWS;

    // ---- load z -> rs ----
#pragma unroll
    for (int j = 0; j < 4; j++) {
        int g = tid + j * 512;                       // 2048 float4 granules
        ((float4*)rs)[g] = ((const float4*)(z + (size_t)row0 * D_))[g];
    }
    __syncthreads();

    auto splitPlanes = [&]() {
#pragma unroll
        for (int j = 0; j < 2; j++) {
            int c = tid + j * 512;                   // 1024 chunks of 8 elems
            int r = c >> 5, kc = c & 31;
            const float* src = rs + r * 256 + kc * 8;
            int phys = kc ^ (r & 7);
            u16 h[8], m[8], l[8];
#pragma unroll
            for (int e = 0; e < 8; e++) {
                float x = src[e];
                h[e] = f2bf(x);
                float r1 = x - bf2f(h[e]);
                m[e] = f2bf(r1);
                r1 -= bf2f(m[e]);
                l[e] = f2bf(r1);
            }
            int o = r * 256 + phys * 8;
            *(ushort4*)(pl0 + o)     = make_ushort4(h[0], h[1], h[2], h[3]);
            *(ushort4*)(pl0 + o + 4) = make_ushort4(h[4], h[5], h[6], h[7]);
            *(ushort4*)(pl1 + o)     = make_ushort4(m[0], m[1], m[2], m[3]);
            *(ushort4*)(pl1 + o + 4) = make_ushort4(m[4], m[5], m[6], m[7]);
            *(ushort4*)(pl2 + o)     = make_ushort4(l[0], l[1], l[2], l[3]);
            *(ushort4*)(pl2 + o + 4) = make_ushort4(l[4], l[5], l[6], l[7]);
        }
    };
    splitPlanes();
    __syncthreads();

    for (int q = 0; q < Q_; q++) {
        const float* cnq = cnorm + (size_t)q * K_;

        u64 best8[2][4];
#pragma unroll
        for (int mf = 0; mf < 2; mf++)
#pragma unroll
            for (int r = 0; r < 4; r++) best8[mf][r] = ~0ull;

        // ---- distance MFMA: two 128-col halves per wave ----
#pragma unroll
        for (int half = 0; half < 2; half++) {
            const int colh = wv * 256 + half * 128;
            const int cg0  = colh >> 4;              // 16-col group base
            f32x4 acc[2][8];
#pragma unroll
            for (int mf = 0; mf < 2; mf++)
#pragma unroll
                for (int n = 0; n < 8; n++) acc[mf][n] = (f32x4){0.f, 0.f, 0.f, 0.f};

            for (int k = 0; k < 8; k++) {
                // A fragments (LDS, swizzled)
                bf16x8 a0[2], a1[2], a2[2];
#pragma unroll
                for (int mf = 0; mf < 2; mf++) {
                    int r = (lane & 15) + mf * 16;
                    int phys = (k * 4 + (lane >> 4)) ^ (r & 7);
                    int o = r * 256 + phys * 8;
                    a0[mf] = *(const bf16x8*)(pl0 + o);
                    a1[mf] = *(const bf16x8*)(pl1 + o);
                    a2[mf] = *(const bf16x8*)(pl2 + o);
                }
#pragma unroll
                for (int n = 0; n < 8; n++) {
                    // fragment-packed: group = q*1024 + (cg0+n)*8 + k
                    size_t fb = (((size_t)(q << 10) + (cg0 + n) * 8 + k) << 9)
                                + lane * 8;
                    bf16x8 b0 = *(const bf16x8*)(cbF0 + fb);
                    bf16x8 b1 = *(const bf16x8*)(cbF1 + fb);
                    bf16x8 b2 = *(const bf16x8*)(cbF2 + fb);
                    __builtin_amdgcn_s_setprio(1);
#pragma unroll
                    for (int mf = 0; mf < 2; mf++) {
                        acc[mf][n] = MFMA_BF16(a0[mf], b0, acc[mf][n], 0, 0, 0);
                        acc[mf][n] = MFMA_BF16(a1[mf], b0, acc[mf][n], 0, 0, 0);
                        acc[mf][n] = MFMA_BF16(a0[mf], b1, acc[mf][n], 0, 0, 0);
                        acc[mf][n] = MFMA_BF16(a1[mf], b1, acc[mf][n], 0, 0, 0);
                        acc[mf][n] = MFMA_BF16(a2[mf], b0, acc[mf][n], 0, 0, 0);
                        acc[mf][n] = MFMA_BF16(a0[mf], b2, acc[mf][n], 0, 0, 0);
                    }
                    __builtin_amdgcn_s_setprio(0);
                }
            }
            // fold this half into per-(mf,r) best
#pragma unroll
            for (int n = 0; n < 8; n++) {
                int col = colh + n * 16 + (lane & 15);
                float cn = cnq[col];
#pragma unroll
                for (int mf = 0; mf < 2; mf++)
#pragma unroll
                    for (int r = 0; r < 4; r++) {
                        float d = cn - 2.0f * acc[mf][n][r];
                        u64 p = ((u64)fkey(d) << 32) | (unsigned)col;
                        if (p < best8[mf][r]) best8[mf][r] = p;
                    }
            }
        }

        // ---- cross-lane (16 cols) then cross-wave argmin ----
#pragma unroll
        for (int mf = 0; mf < 2; mf++)
#pragma unroll
            for (int r = 0; r < 4; r++) {
                u64 p = best8[mf][r];
#pragma unroll
                for (int msk = 1; msk <= 8; msk <<= 1) {
                    u64 o = __shfl_xor(p, msk, 64);
                    if (o < p) p = o;
                }
                if ((lane & 15) == 0)
                    wmin[mf * 16 + (lane >> 4) * 4 + r][wv] = p;
            }
        __syncthreads();
        if (tid < ROWS) {
            u64 m = wmin[tid][0];
#pragma unroll
            for (int w2 = 1; w2 < 8; w2++) { u64 o = wmin[tid][w2]; if (o < m) m = o; }
            winner[tid] = m;
            out_idx[(size_t)(row0 + tid) * Q_ + q] = (float)(unsigned)(m & 0xffffffffu);
        }
        __syncthreads();

        // ---- residual update + loss ----
        float lsum = 0.f;
#pragma unroll
        for (int j = 0; j < 4; j++) {
            int g = tid + j * 512;
            int r = g >> 6;
            unsigned idx = (unsigned)(winner[r] & 0xffffffffu);
            const float4 cv = *(const float4*)(CB + ((size_t)q * K_ + idx) * D_ + (g & 63) * 4);
            float4 rv = ((float4*)rs)[g];
            float dx = rv.x - cv.x, dy = rv.y - cv.y,
                  dz = rv.z - cv.z, dw = rv.w - cv.w;
            lsum += dx * dx + dy * dy + dz * dz + dw * dw;
            ((float4*)rs)[g] = make_float4(dx, dy, dz, dw);
        }
#pragma unroll
        for (int o = 32; o > 0; o >>= 1) lsum += __shfl_down(lsum, o, 64);
        if (lane == 0) atomicAdd(&loss_acc[q], lsum);
        __syncthreads();

        if (q < Q_ - 1) { splitPlanes(); __syncthreads(); }
    }

    // ---- quant = z - resid_final -> bf16 plane for decoder ----
#pragma unroll
    for (int j = 0; j < 2; j++) {
        int c = tid + j * 512;
        int e0 = c * 8;
        const float* zp = z + (size_t)row0 * D_ + e0;
        float4 za = *(const float4*)zp, zb = *(const float4*)(zp + 4);
        float4 ra = *(const float4*)(rs + e0), rb = *(const float4*)(rs + e0 + 4);
        *(ushort4*)(qplane + (size_t)row0 * D_ + e0) =
            make_ushort4(f2bf(za.x - ra.x), f2bf(za.y - ra.y),
                         f2bf(za.z - ra.z), f2bf(za.w - ra.w));
        *(ushort4*)(qplane + (size_t)row0 * D_ + e0 + 4) =
            make_ushort4(f2bf(zb.x - rb.x), f2bf(zb.y - rb.y),
                         f2bf(zb.z - rb.z), f2bf(zb.w - rb.w));
    }
}

// =====================================================================
// gemm2: 256x128 tile, 512 threads, 2-phase prefetch, XCD swizzle
// =====================================================================
template<int NSA, int NSB, int RELU, int NSO, int WF32>
__global__ __launch_bounds__(512)
void gemm2(const u16* __restrict__ A0, const u16* __restrict__ A1,
           const u16* __restrict__ A2,
           const u16* __restrict__ B0, const u16* __restrict__ B1,
           const u16* __restrict__ B2,
           const float* __restrict__ bias,
           float* __restrict__ C,
           u16* __restrict__ C0, u16* __restrict__ C1, u16* __restrict__ C2,
           int N, int Kd)
{
    constexpr int HALF = NSA * 16384 + NSB * 8192;
    __shared__ __align__(16) char smem[2 * HALF];
    const int tid  = threadIdx.x;
    const int lane = tid & 63;
    const int wid  = tid >> 6;
    const int wr   = wid >> 1, wc = wid & 1;

    const int nwg  = gridDim.x;
    const int orig = blockIdx.x;
    const int xcd  = orig & 7;
    const int q8 = nwg >> 3, r8 = nwg & 7;
    const int wgid = (xcd < r8 ? xcd * (q8 + 1)
                               : r8 * (q8 + 1) + (xcd - r8) * q8) + (orig >> 3);
    const int gx = N >> 7;
    const int bx = wgid % gx;
    const int by = wgid / gx;
    const int row0 = by * 256;
    const int col0 = bx * 128;

    const u16* asrc[3][2];
    const u16* bsrc[3];
#pragma unroll
    for (int h = 0; h < 2; h++) {
        int ch = h * 512 + tid;
        int r  = ch >> 2;
        int kc = (ch & 3) ^ ((r >> 1) & 3);
        size_t off = (size_t)(row0 + r) * Kd + kc * 8;
        asrc[0][h] = A0 + off;
        if constexpr (NSA >= 3) { asrc[1][h] = A1 + off; asrc[2][h] = A2 + off; }
    }
    {
        int r  = tid >> 2;
        int kc = (tid & 3) ^ ((r >> 1) & 3);
        size_t off = (size_t)(col0 + r) * Kd + kc * 8;
        bsrc[0] = B0 + off;
        if constexpr (NSB >= 3) { bsrc[1] = B1 + off; bsrc[2] = B2 + off; }
    }

    auto stage = [&](int c) {
        char* base = smem + c * HALF;
#pragma unroll
        for (int s = 0; s < NSA; s++)
#pragma unroll
            for (int h = 0; h < 2; h++) {
                gload_lds16(asrc[s][h], base + s * 16384 + (h * 512 + tid) * 16);
                asrc[s][h] += 32;
            }
#pragma unroll
        for (int s = 0; s < NSB; s++) {
            gload_lds16(bsrc[s], base + NSA * 16384 + s * 8192 + tid * 16);
            bsrc[s] += 32;
        }
    };

    f32x4 acc[4][4];
#pragma unroll
    for (int m = 0; m < 4; m++)
#pragma unroll
        for (int n = 0; n < 4; n++) acc[m][n] = (f32x4){0.f, 0.f, 0.f, 0.f};

    const unsigned fro = (unsigned)((lane & 15) * 64
        + (((lane >> 4) ^ (((lane & 15) >> 1) & 3)) * 16));

    const int nt = Kd >> 5;
    int cur = 0;
    stage(0);
    __syncthreads();

    for (int t = 0; t < nt; t++) {
        if (t + 1 < nt) stage(cur ^ 1);
        const char* base = smem + cur * HALF;
        bf16x8 bfr[4][3];
#pragma unroll
        for (int n = 0; n < 4; n++)
#pragma unroll
            for (int s = 0; s < NSB; s++)
                bfr[n][s] = *(const bf16x8*)(base + NSA * 16384 + s * 8192
                                             + (wc * 64 + n * 16) * 64 + fro);
#pragma unroll
        for (int m = 0; m < 4; m++) {
            bf16x8 af[3];
#pragma unroll
            for (int s = 0; s < NSA; s++)
                af[s] = *(const bf16x8*)(base + s * 16384
                                         + (wr * 64 + m * 16) * 64 + fro);
#pragma unroll
            for (int n = 0; n < 4; n++) {
                acc[m][n] = MFMA_BF16(af[0], bfr[n][0], acc[m][n], 0, 0, 0);
                if constexpr (NSA >= 3 && NSB >= 3) {
                    acc[m][n] = MFMA_BF16(af[1], bfr[n][0], acc[m][n], 0, 0, 0);
                    acc[m][n] = MFMA_BF16(af[0], bfr[n][1], acc[m][n], 0, 0, 0);
                    acc[m][n] = MFMA_BF16(af[1], bfr[n][1], acc[m][n], 0, 0, 0);
                    acc[m][n] = MFMA_BF16(af[2], bfr[n][0], acc[m][n], 0, 0, 0);
                    acc[m][n] = MFMA_BF16(af[0], bfr[n][2], acc[m][n], 0, 0, 0);
                }
            }
        }
        __syncthreads();
        cur ^= 1;
    }

    const int rbase = row0 + wr * 64 + (lane >> 4) * 4;
    const int cbase = col0 + wc * 64 + (lane & 15);
    float bv[4];
#pragma unroll
    for (int n = 0; n < 4; n++) bv[n] = bias[cbase + n * 16];
#pragma unroll
    for (int m = 0; m < 4; m++)
#pragma unroll
        for (int n = 0; n < 4; n++)
#pragma unroll
            for (int r = 0; r < 4; r++) {
                float o = acc[m][n][r] + bv[n];
                if constexpr (RELU) o = fmaxf(o, 0.f);
                size_t off = (size_t)(rbase + m * 16 + r) * N + (cbase + n * 16);
                if constexpr (WF32) C[off] = o;
                if constexpr (NSO >= 1) {
                    u16 p0 = f2bf(o);
                    C0[off] = p0;
                    if constexpr (NSO >= 3) {
                        float r1 = o - bf2f(p0);
                        u16 p1 = f2bf(r1);
                        C1[off] = p1;
                        r1 -= bf2f(p1);
                        C2[off] = f2bf(r1);
                    }
                }
            }
}

// =====================================================================
// gemm_mfma: 128x128 / 4-wave kernel (small-N GEMMs: enc G2/G3, dec1)
// =====================================================================
template<int NSA, int NSB, int RELU, int NSO, int WF32>
__global__ __launch_bounds__(256)
void gemm_mfma(const u16* __restrict__ A0, const u16* __restrict__ A1,
               const u16* __restrict__ A2,
               const u16* __restrict__ B0, const u16* __restrict__ B1,
               const u16* __restrict__ B2,
               const float* __restrict__ bias,
               float* __restrict__ C,
               u16* __restrict__ C0, u16* __restrict__ C1, u16* __restrict__ C2,
               int M, int N, int Kd)
{
    constexpr int NP = NSA + NSB;
    __shared__ __align__(16) char smem[NP * 8192];
    const int tid  = threadIdx.x;
    const int lane = tid & 63;
    const int wid  = tid >> 6;
    const int wr   = wid >> 1, wc = wid & 1;
    const int row0 = blockIdx.y * 128;
    const int col0 = blockIdx.x * 128;

    const u16* asrc[3][2];
    const u16* bsrc[3][2];
#pragma unroll
    for (int h = 0; h < 2; h++) {
        int ch = h * 256 + tid;
        int r  = ch >> 2;
        int kc = (ch & 3) ^ ((r >> 1) & 3);
        size_t aoff = (size_t)(row0 + r) * Kd + kc * 8;
        size_t boff = (size_t)(col0 + r) * Kd + kc * 8;
        asrc[0][h] = A0 + aoff;
        if constexpr (NSA >= 3) { asrc[1][h] = A1 + aoff; asrc[2][h] = A2 + aoff; }
        bsrc[0][h] = B0 + boff;
        if constexpr (NSB >= 3) { bsrc[1][h] = B1 + boff; bsrc[2][h] = B2 + boff; }
    }

    f32x4 acc[4][4];
#pragma unroll
    for (int m = 0; m < 4; m++)
#pragma unroll
        for (int n = 0; n < 4; n++) acc[m][n] = (f32x4){0.f, 0.f, 0.f, 0.f};

    const unsigned fro = (unsigned)((lane & 15) * 64
        + (((lane >> 4) ^ (((lane & 15) >> 1) & 3)) * 16));

    for (int k0 = 0; k0 < Kd; k0 += 32) {
#pragma unroll
        for (int s = 0; s < NSA; s++)
#pragma unroll
            for (int h = 0; h < 2; h++) {
                gload_lds16(asrc[s][h], smem + s * 8192 + (h * 256 + tid) * 16);
                asrc[s][h] += 32;
            }
#pragma unroll
        for (int s = 0; s < NSB; s++)
#pragma unroll
            for (int h = 0; h < 2; h++) {
                gload_lds16(bsrc[s][h],
                            smem + (NSA + s) * 8192 + (h * 256 + tid) * 16);
                bsrc[s][h] += 32;
            }
        __syncthreads();

        bf16x8 bfr[4][3];
#pragma unroll
        for (int n = 0; n < 4; n++)
#pragma unroll
            for (int s = 0; s < NSB; s++)
                bfr[n][s] = *(const bf16x8*)(smem + (NSA + s) * 8192
                                             + (wc * 64 + n * 16) * 64 + fro);
#pragma unroll
        for (int m = 0; m < 4; m++) {
            bf16x8 af[3];
#pragma unroll
            for (int s = 0; s < NSA; s++)
                af[s] = *(const bf16x8*)(smem + s * 8192
                                         + (wr * 64 + m * 16) * 64 + fro);
#pragma unroll
            for (int n = 0; n < 4; n++) {
                acc[m][n] = MFMA_BF16(af[0], bfr[n][0], acc[m][n], 0, 0, 0);
                if constexpr (NSA >= 3 && NSB >= 3) {
                    acc[m][n] = MFMA_BF16(af[1], bfr[n][0], acc[m][n], 0, 0, 0);
                    acc[m][n] = MFMA_BF16(af[0], bfr[n][1], acc[m][n], 0, 0, 0);
                    acc[m][n] = MFMA_BF16(af[1], bfr[n][1], acc[m][n], 0, 0, 0);
                    acc[m][n] = MFMA_BF16(af[2], bfr[n][0], acc[m][n], 0, 0, 0);
                    acc[m][n] = MFMA_BF16(af[0], bfr[n][2], acc[m][n], 0, 0, 0);
                }
            }
        }
        __syncthreads();
    }

    const int rbase = row0 + wr * 64 + (lane >> 4) * 4;
    const int cbase = col0 + wc * 64 + (lane & 15);
    float bv[4];
#pragma unroll
    for (int n = 0; n < 4; n++) bv[n] = bias[cbase + n * 16];
#pragma unroll
    for (int m = 0; m < 4; m++)
#pragma unroll
        for (int n = 0; n < 4; n++)
#pragma unroll
            for (int r = 0; r < 4; r++) {
                float o = acc[m][n][r] + bv[n];
                if constexpr (RELU) o = fmaxf(o, 0.f);
                size_t off = (size_t)(rbase + m * 16 + r) * N + (cbase + n * 16);
                if constexpr (WF32) C[off] = o;
                if constexpr (NSO >= 1) {
                    u16 p0 = f2bf(o);
                    C0[off] = p0;
                    if constexpr (NSO >= 3) {
                        float r1 = o - bf2f(p0);
                        u16 p1 = f2bf(r1);
                        C1[off] = p1;
                        r1 -= bf2f(p1);
                        C2[off] = f2bf(r1);
                    }
                }
            }
}

// ---------------- weight transpose + split prepass ----------------
template<int NS>
__global__ __launch_bounds__(256)
void wsplit_kernel(const float* __restrict__ W, u16* __restrict__ T0,
                   u16* __restrict__ T1, u16* __restrict__ T2, int Kd, int N)
{
    __shared__ float t[32][33];
    const int tx = threadIdx.x & 31, ty = threadIdx.x >> 5;
    const int n0 = blockIdx.x * 32, k0 = blockIdx.y * 32;
#pragma unroll
    for (int r = 0; r < 4; r++)
        t[ty + r * 8][tx] = W[(size_t)(k0 + ty + r * 8) * N + n0 + tx];
    __syncthreads();
#pragma unroll
    for (int r = 0; r < 4; r++) {
        int n = n0 + ty + r * 8, k = k0 + tx;
        float v = t[tx][ty + r * 8];
        u16 h = f2bf(v);
        T0[(size_t)n * Kd + k] = h;
        if constexpr (NS >= 2) {
            float rr = v - bf2f(h);
            u16 m = f2bf(rr);
            T1[(size_t)n * Kd + k] = m;
            if constexpr (NS >= 3) { rr -= bf2f(m); T2[(size_t)n * Kd + k] = f2bf(rr); }
        }
    }
}

// ---------------- elementwise 3-plane split (x) ----------------
__global__ __launch_bounds__(256)
void esplit3_kernel(const float* __restrict__ src, u16* __restrict__ s0,
                    u16* __restrict__ s1, u16* __restrict__ s2)
{
    size_t i = (size_t)blockIdx.x * 256 + threadIdx.x;
    float4 v = ((const float4*)src)[i];
    float x[4] = {v.x, v.y, v.z, v.w};
    u16 h[4], m[4], l[4];
#pragma unroll
    for (int e = 0; e < 4; e++) {
        h[e] = f2bf(x[e]);
        float r1 = x[e] - bf2f(h[e]);
        m[e] = f2bf(r1);
        r1 -= bf2f(m[e]);
        l[e] = f2bf(r1);
    }
    ((ushort4*)s0)[i] = make_ushort4(h[0], h[1], h[2], h[3]);
    ((ushort4*)s1)[i] = make_ushort4(m[0], m[1], m[2], m[3]);
    ((ushort4*)s2)[i] = make_ushort4(l[0], l[1], l[2], l[3]);
}

__global__ void cnorm_kernel(const float* __restrict__ cb, float* __restrict__ cn)
{
    const int lane = threadIdx.x & 63;
    const int w = threadIdx.x >> 6;
    const int row = blockIdx.x * 4 + w;
    const float4 v = *(const float4*)(&cb[(size_t)row * D_ + lane * 4]);
    float s = v.x * v.x + v.y * v.y + v.z * v.z + v.w * v.w;
#pragma unroll
    for (int o = 32; o > 0; o >>= 1) s += __shfl_down(s, o, 64);
    if (lane == 0) cn[row] = s;
}

__global__ void loss_write_kernel(const float* __restrict__ loss_acc,
                                  float* __restrict__ out_loss)
{
    int q = threadIdx.x;
    if (q < Q_) out_loss[q] = loss_acc[q] * (1.0f / ((float)B_ * (float)D_));
}

// ---------------- launch ----------------
extern "C" void kernel_launch(void* const* d_in, const int* in_sizes, int n_in,
                              void* d_out, int out_size, void* d_ws, size_t ws_size,
                              hipStream_t stream)
{
    const float* x    = (const float*)d_in[0];
    const float* e_w0 = (const float*)d_in[1];
    const float* e_b0 = (const float*)d_in[2];
    const float* e_w1 = (const float*)d_in[3];
    const float* e_b1 = (const float*)d_in[4];
    const float* e_w2 = (const float*)d_in[5];
    const float* e_b2 = (const float*)d_in[6];
    const float* d_w0 = (const float*)d_in[7];
    const float* d_b0 = (const float*)d_in[8];
    const float* d_w1 = (const float*)d_in[9];
    const float* d_b1 = (const float*)d_in[10];
    const float* d_w2 = (const float*)d_in[11];
    const float* d_b2 = (const float*)d_in[12];
    const float* codebooks = (const float*)d_in[13];

    float* out = (float*)d_out;
    float* out_decoded = out;
    float* out_idx     = out + (size_t)B_ * IN_;
    float* out_loss    = out_idx + (size_t)B_ * Q_;

    char* w = (char*)d_ws;
    auto alloc = [&](size_t bytes) {
        char* r = w; w += (bytes + 255) & ~(size_t)255; return r;
    };
    u16* ew0t = (u16*)alloc((size_t)3 * IN_ * H0_ * 2);
    u16* ew1t = (u16*)alloc((size_t)3 * H0_ * H1_ * 2);
    u16* ew2t = (u16*)alloc((size_t)3 * H1_ * D_ * 2);
    u16* dw0t = (u16*)alloc((size_t)D_ * H1_ * 2);
    u16* dw1t = (u16*)alloc((size_t)H1_ * H0_ * 2);
    u16* dw2t = (u16*)alloc((size_t)H0_ * IN_ * 2);
    u16* cbF  = (u16*)alloc((size_t)3 * Q_ * K_ * D_ * 2);   // fragment-packed
    float* cnorm = (float*)alloc((size_t)Q_ * K_ * 4);
    float* loss  = (float*)alloc(64);
    float* zbuf  = (float*)alloc((size_t)B_ * D_ * 4);
    u16* qplane  = (u16*)alloc((size_t)B_ * D_ * 2);
    char* regX = alloc((size_t)3 * B_ * IN_ * 2);
    u16* xp0 = (u16*)regX;
    u16* xp1 = xp0 + (size_t)B_ * IN_;
    u16* xp2 = xp1 + (size_t)B_ * IN_;
    u16* h1p0 = (u16*)regX;                       // after G1 consumed
    u16* h1p1 = h1p0 + (size_t)B_ * H1_;
    u16* h1p2 = h1p1 + (size_t)B_ * H1_;
    u16* dh1p = h1p2 + (size_t)B_ * H1_;
    u16* dh0p = dh1p + (size_t)B_ * H1_;
    char* regH = alloc((size_t)3 * B_ * H0_ * 2);
    u16* h0p0 = (u16*)regH;
    u16* h0p1 = h0p0 + (size_t)B_ * H0_;
    u16* h0p2 = h0p1 + (size_t)B_ * H0_;

    const size_t ew0s = (size_t)IN_ * H0_, ew1s = (size_t)H0_ * H1_,
                 ew2s = (size_t)H1_ * D_, cbsz = (size_t)Q_ * K_ * D_;

    // ---- init + prepasses ----
    hipMemsetAsync(loss, 0, 64, stream);
    esplit3_kernel<<<(size_t)B_ * IN_ / 1024, 256, 0, stream>>>(x, xp0, xp1, xp2);
    cbpack_kernel<<<2048, 256, 0, stream>>>(
        codebooks, cbF, cbF + cbsz, cbF + 2 * cbsz);
    wsplit_kernel<3><<<dim3(H0_ / 32, IN_ / 32), 256, 0, stream>>>(
        e_w0, ew0t, ew0t + ew0s, ew0t + 2 * ew0s, IN_, H0_);
    wsplit_kernel<3><<<dim3(H1_ / 32, H0_ / 32), 256, 0, stream>>>(
        e_w1, ew1t, ew1t + ew1s, ew1t + 2 * ew1s, H0_, H1_);
    wsplit_kernel<3><<<dim3(D_ / 32, H1_ / 32), 256, 0, stream>>>(
        e_w2, ew2t, ew2t + ew2s, ew2t + 2 * ew2s, H1_, D_);
    wsplit_kernel<1><<<dim3(H1_ / 32, D_ / 32), 256, 0, stream>>>(
        d_w0, dw0t, nullptr, nullptr, D_, H1_);
    wsplit_kernel<1><<<dim3(H0_ / 32, H1_ / 32), 256, 0, stream>>>(
        d_w1, dw1t, nullptr, nullptr, H1_, H0_);
    wsplit_kernel<1><<<dim3(IN_ / 32, H0_ / 32), 256, 0, stream>>>(
        d_w2, dw2t, nullptr, nullptr, H0_, IN_);
    cnorm_kernel<<<(Q_ * K_) / 4, 256, 0, stream>>>(codebooks, cnorm);

    // ---- encoder ----
    gemm2<3, 3, 1, 3, 0><<<(H0_ / 128) * (B_ / 256), 512, 0, stream>>>(
        xp0, xp1, xp2, ew0t, ew0t + ew0s, ew0t + 2 * ew0s, e_b0,
        nullptr, h0p0, h0p1, h0p2, H0_, IN_);
    gemm_mfma<3, 3, 1, 3, 0><<<dim3(H1_ / 128, B_ / 128), 256, 0, stream>>>(
        h0p0, h0p1, h0p2, ew1t, ew1t + ew1s, ew1t + 2 * ew1s, e_b1,
        nullptr, h1p0, h1p1, h1p2, B_, H1_, H0_);
    gemm_mfma<3, 3, 0, 0, 1><<<dim3(D_ / 128, B_ / 128), 256, 0, stream>>>(
        h1p0, h1p1, h1p2, ew2t, ew2t + ew2s, ew2t + 2 * ew2s, e_b2,
        zbuf, nullptr, nullptr, nullptr, B_, D_, H1_);

    // ---- fused residual VQ ----
    vq_fused<<<B_ / ROWS, 512, 0, stream>>>(
        zbuf, codebooks, cbF, cbF + cbsz, cbF + 2 * cbsz, cnorm,
        qplane, out_idx, loss);
    loss_write_kernel<<<1, 64, 0, stream>>>(loss, out_loss);

    // ---- decoder ----
    gemm_mfma<1, 1, 1, 1, 0><<<dim3(H1_ / 128, B_ / 128), 256, 0, stream>>>(
        qplane, nullptr, nullptr, dw0t, nullptr, nullptr, d_b0,
        nullptr, dh1p, nullptr, nullptr, B_, H1_, D_);
    gemm2<1, 1, 1, 1, 0><<<(H0_ / 128) * (B_ / 256), 512, 0, stream>>>(
        dh1p, nullptr, nullptr, dw1t, nullptr, nullptr, d_b1,
        nullptr, dh0p, nullptr, nullptr, H0_, H1_);
    gemm2<1, 1, 0, 0, 1><<<(IN_ / 128) * (B_ / 256), 512, 0, stream>>>(
        dh0p, nullptr, nullptr, dw2t, nullptr, nullptr, d_b2,
        out_decoded, nullptr, nullptr, nullptr, IN_, H0_);
}